// Round 1
// 828.356 us; speedup vs baseline: 1.0507x; 1.0507x over previous
//
#include <hip/hip_runtime.h>
#include <hip/hip_bf16.h>

typedef unsigned short u16;
typedef unsigned int   u32;

using frag_ab = __attribute__((ext_vector_type(8))) short;  // 8 bf16
using frag_cd = __attribute__((ext_vector_type(4))) float;  // 4 fp32

// ---------- bf16 helpers ----------
__device__ __forceinline__ float bf2f(u16 u) {
    union { u32 i; float f; } v; v.i = ((u32)u) << 16; return v.f;
}
__device__ __forceinline__ u16 f2bf(float f) {
    __hip_bfloat16 h = __float2bfloat16(f);
    u16 u; __builtin_memcpy(&u, &h, 2); return u;
}
__device__ __forceinline__ float lo2f(u32 u) { union { u32 i; float f; } v; v.i = u << 16; return v.f; }
__device__ __forceinline__ float hi2f(u32 u) { union { u32 i; float f; } v; v.i = u & 0xffff0000u; return v.f; }
__device__ __forceinline__ void unpack8(uint4 v, float* f) {
    f[0]=lo2f(v.x); f[1]=hi2f(v.x); f[2]=lo2f(v.y); f[3]=hi2f(v.y);
    f[4]=lo2f(v.z); f[5]=hi2f(v.z); f[6]=lo2f(v.w); f[7]=hi2f(v.w);
}
__device__ __forceinline__ void load4f(const u16* p, float* f) {
    ushort4 v = *reinterpret_cast<const ushort4*>(p);
    f[0]=bf2f(v.x); f[1]=bf2f(v.y); f[2]=bf2f(v.z); f[3]=bf2f(v.w);
}
__device__ __forceinline__ void store4bf(u16* p, const float* f) {
    ushort4 v; v.x=f2bf(f[0]); v.y=f2bf(f[1]); v.z=f2bf(f[2]); v.w=f2bf(f[3]);
    *reinterpret_cast<ushort4*>(p) = v;
}
__device__ __forceinline__ u32 pack2(float a, float b) {
    return (u32)f2bf(a) | ((u32)f2bf(b) << 16);
}

// async global->LDS DMA, 16B per lane; lds dest = wave-uniform base + lane*16
__device__ __forceinline__ void gld16(const u16* g, u16* l) {
    __builtin_amdgcn_global_load_lds(
        (const __attribute__((address_space(1))) u32*)g,
        (__attribute__((address_space(3))) u32*)l, 16, 0, 0);
}

// ---------- block reduction (256 threads = 4 waves) ----------
__device__ __forceinline__ void block_reduce2(float& s, float& ss, float* red) {
    #pragma unroll
    for (int off = 32; off > 0; off >>= 1) {
        s  += __shfl_down(s, off, 64);
        ss += __shfl_down(ss, off, 64);
    }
    int wv = threadIdx.x >> 6, ln = threadIdx.x & 63;
    if (ln == 0) { red[wv*2] = s; red[wv*2+1] = ss; }
    __syncthreads();
    s  = red[0] + red[2] + red[4] + red[6];
    ss = red[1] + red[3] + red[5] + red[7];
    __syncthreads();
}

// ---------- fp32 -> bf16 conversion (n4 = n/4 float4 groups) ----------
__global__ __launch_bounds__(256) void convert_kernel(
    const float* __restrict__ in, u16* __restrict__ out, int n4)
{
    int i = blockIdx.x * 256 + threadIdx.x;
    if (i < n4) {
        float4 v = reinterpret_cast<const float4*>(in)[i];
        ushort4 o; o.x=f2bf(v.x); o.y=f2bf(v.y); o.z=f2bf(v.z); o.w=f2bf(v.w);
        reinterpret_cast<ushort4*>(out)[i] = o;
    }
}

// ---------- pad concat(theta,mag) -> Abuf (64 x 1056 bf16) ----------
__global__ __launch_bounds__(256) void apad_kernel(
    const float* __restrict__ gth, const float* __restrict__ gmag,
    u16* __restrict__ Abuf)
{
    const int r = blockIdx.x;             // 0..63
    const int tid = threadIdx.x;
    for (int c0 = tid*4; c0 < 1056; c0 += 1024) {
        float f[4];
        #pragma unroll
        for (int i = 0; i < 4; ++i) {
            int c = c0 + i;
            f[i] = (c < 1024) ? gth[(size_t)r*1024 + c] : (c == 1024 ? gmag[r] : 0.f);
        }
        store4bf(Abuf + (size_t)r*1056 + c0, f);
    }
}

// ---------- pad up_W (2048 x 1025 fp32) -> Bbuf (2048 x 1056 bf16) ----------
__global__ __launch_bounds__(256) void wpad_kernel(
    const float* __restrict__ upW, u16* __restrict__ Bbuf)
{
    const int r = blockIdx.x;             // 0..2047
    const int tid = threadIdx.x;
    for (int c0 = tid*4; c0 < 1056; c0 += 1024) {
        float f[4];
        #pragma unroll
        for (int i = 0; i < 4; ++i) {
            int c = c0 + i;
            f[i] = (c < 1025) ? upW[(size_t)r*1025 + c] : 0.f;
        }
        store4bf(Bbuf + (size_t)r*1056 + c0, f);
    }
}

// ---------- setup: cos/sin tables ----------
__global__ __launch_bounds__(256) void setup_kernel(
    const float* __restrict__ sheaf_th, const float* __restrict__ gth,
    const float* __restrict__ gmag, const float* __restrict__ gwts,
    const float* __restrict__ strength, float* __restrict__ sheaf_cs,
    float* __restrict__ gist_cs)
{
    int bx = blockIdx.x, tid = threadIdx.x;
    if (bx < 4) {
        for (int j = tid; j < 1024; j += 256) {
            float th = sheaf_th[bx*1024 + j];
            sheaf_cs[bx*1024 + j]        = cosf(th);
            sheaf_cs[4096 + bx*1024 + j] = sinf(th);
        }
    } else {
        int b = bx - 4;
        float w[16], wsum = 0.f;
        #pragma unroll
        for (int k = 0; k < 16; ++k) {
            w[k] = gwts[b*16+k] * gmag[b*16+k];
            wsum += w[k];
        }
        float inv = 1.f / (wsum + 1e-8f);
        float sig = 1.f / (1.f + expf(-strength[0]));
        for (int j = tid; j < 1024; j += 256) {
            float th = 0.f;
            #pragma unroll
            for (int k = 0; k < 16; ++k)
                th += w[k] * inv * gth[(size_t)(b*16+k)*1024 + j];
            th *= sig;
            gist_cs[b*1024 + j]        = cosf(th);
            gist_cs[4096 + b*1024 + j] = sinf(th);
        }
    }
}

// ---------- LN over rows of 2048: fp32 in -> bf16 out ----------
__global__ __launch_bounds__(256) void ln_kernel(
    const float* __restrict__ in, const float* __restrict__ w,
    const float* __restrict__ b, u16* __restrict__ out)
{
    __shared__ float red[8];
    const size_t base = (size_t)blockIdx.x * 2048;
    const int e0 = threadIdx.x * 8;
    float x[8];
    *reinterpret_cast<float4*>(&x[0]) = *reinterpret_cast<const float4*>(in + base + e0);
    *reinterpret_cast<float4*>(&x[4]) = *reinterpret_cast<const float4*>(in + base + e0 + 4);
    float s = 0.f, ss = 0.f;
    #pragma unroll
    for (int i = 0; i < 8; ++i) { s += x[i]; ss += x[i]*x[i]; }
    block_reduce2(s, ss, red);
    const float mu = s * (1.f/2048.f);
    const float rin = rsqrtf(ss * (1.f/2048.f) - mu*mu + 1e-5f);
    float wv[8], bv[8];
    *reinterpret_cast<float4*>(&wv[0]) = *reinterpret_cast<const float4*>(w + e0);
    *reinterpret_cast<float4*>(&wv[4]) = *reinterpret_cast<const float4*>(w + e0 + 4);
    *reinterpret_cast<float4*>(&bv[0]) = *reinterpret_cast<const float4*>(b + e0);
    *reinterpret_cast<float4*>(&bv[4]) = *reinterpret_cast<const float4*>(b + e0 + 4);
    float o[8];
    #pragma unroll
    for (int i = 0; i < 8; ++i) o[i] = (x[i]-mu)*rin*wv[i] + bv[i];
    uint4 st = { pack2(o[0],o[1]), pack2(o[2],o[3]), pack2(o[4],o[5]), pack2(o[6],o[7]) };
    *reinterpret_cast<uint4*>(out + base + e0) = st;
}

// ---------- sheaf: pre = x1 - |alpha| * (4*x1 - sum rot_inv(shift(x1))) ----------
__global__ __launch_bounds__(256) void sheaf_kernel(
    const u16* __restrict__ x1, const float* __restrict__ scs,
    const float* __restrict__ alpha_p, u16* __restrict__ pre)
{
    const int row = blockIdx.x;
    const int t = row & 2047;
    const int j0 = threadIdx.x * 4;
    const size_t base = (size_t)row * 2048;
    const float a = fabsf(alpha_p[0]);

    float xr[4], xi[4];
    load4f(x1 + base + j0, xr);
    load4f(x1 + base + 1024 + j0, xi);
    float lr[4], li[4];
    #pragma unroll
    for (int m = 0; m < 4; ++m) { lr[m] = 4.f*xr[m]; li[m] = 4.f*xi[m]; }

    #pragma unroll
    for (int idx = 0; idx < 4; ++idx) {
        const int sh = 3 - idx;
        if (t >= sh) {
            const float4 c4 = *reinterpret_cast<const float4*>(&scs[idx*1024 + j0]);
            const float4 s4 = *reinterpret_cast<const float4*>(&scs[4096 + idx*1024 + j0]);
            float c[4] = {c4.x, c4.y, c4.z, c4.w};
            float sn[4] = {s4.x, s4.y, s4.z, s4.w};
            float yr[4], yi[4];
            load4f(x1 + base - (size_t)sh*2048 + j0, yr);
            load4f(x1 + base - (size_t)sh*2048 + 1024 + j0, yi);
            #pragma unroll
            for (int m = 0; m < 4; ++m) {
                lr[m] -= yr[m]*c[m] + yi[m]*sn[m];     // rot_inv real
                li[m] -= yi[m]*c[m] - yr[m]*sn[m];     // rot_inv imag
            }
        }
    }
    float pr[4], pi[4];
    #pragma unroll
    for (int m = 0; m < 4; ++m) { pr[m] = xr[m] - a*lr[m]; pi[m] = xi[m] - a*li[m]; }
    store4bf(pre + base + j0, pr);
    store4bf(pre + base + 1024 + j0, pi);
}

// ---------- stage2: xn=LN(xA); g=LN(rot(xn)); xB=xA-xn+g; x2=LN(xB) ----------
__global__ __launch_bounds__(256) void stage2_kernel(
    const u16* __restrict__ xA, const float* __restrict__ gcs,
    const float* __restrict__ lgw, const float* __restrict__ lgb,
    const float* __restrict__ grw, const float* __restrict__ grb,
    const float* __restrict__ gcaw, const float* __restrict__ gcab,
    u16* __restrict__ xB, u16* __restrict__ x2)
{
    __shared__ float red[8];
    const int row = blockIdx.x;
    const int b = row >> 11;
    const int j0 = threadIdx.x * 4;
    const size_t base = (size_t)row * 2048;

    float ar[4], ai[4];
    load4f(xA + base + j0, ar);
    load4f(xA + base + 1024 + j0, ai);

    float s = 0.f, ss = 0.f;
    #pragma unroll
    for (int m = 0; m < 4; ++m) { s += ar[m]+ai[m]; ss += ar[m]*ar[m] + ai[m]*ai[m]; }
    block_reduce2(s, ss, red);
    float mu = s * (1.f/2048.f);
    float rin = rsqrtf(ss * (1.f/2048.f) - mu*mu + 1e-5f);

    float w0[4], b0[4], w1[4], b1[4];
    *reinterpret_cast<float4*>(w0) = *reinterpret_cast<const float4*>(lgw + j0);
    *reinterpret_cast<float4*>(b0) = *reinterpret_cast<const float4*>(lgb + j0);
    *reinterpret_cast<float4*>(w1) = *reinterpret_cast<const float4*>(lgw + 1024 + j0);
    *reinterpret_cast<float4*>(b1) = *reinterpret_cast<const float4*>(lgb + 1024 + j0);
    float xnr[4], xni[4];
    #pragma unroll
    for (int m = 0; m < 4; ++m) {
        xnr[m] = (ar[m]-mu)*rin*w0[m] + b0[m];
        xni[m] = (ai[m]-mu)*rin*w1[m] + b1[m];
    }

    const float4 c4 = *reinterpret_cast<const float4*>(&gcs[b*1024 + j0]);
    const float4 s4 = *reinterpret_cast<const float4*>(&gcs[4096 + b*1024 + j0]);
    float c[4] = {c4.x, c4.y, c4.z, c4.w};
    float sn[4] = {s4.x, s4.y, s4.z, s4.w};
    float rr[4], ri[4];
    #pragma unroll
    for (int m = 0; m < 4; ++m) {
        rr[m] = xnr[m]*c[m] - xni[m]*sn[m];
        ri[m] = xnr[m]*sn[m] + xni[m]*c[m];
    }

    s = 0.f; ss = 0.f;
    #pragma unroll
    for (int m = 0; m < 4; ++m) { s += rr[m]+ri[m]; ss += rr[m]*rr[m] + ri[m]*ri[m]; }
    block_reduce2(s, ss, red);
    float mu2 = s * (1.f/2048.f);
    float rin2 = rsqrtf(ss * (1.f/2048.f) - mu2*mu2 + 1e-5f);

    *reinterpret_cast<float4*>(w0) = *reinterpret_cast<const float4*>(grw + j0);
    *reinterpret_cast<float4*>(b0) = *reinterpret_cast<const float4*>(grb + j0);
    *reinterpret_cast<float4*>(w1) = *reinterpret_cast<const float4*>(grw + 1024 + j0);
    *reinterpret_cast<float4*>(b1) = *reinterpret_cast<const float4*>(grb + 1024 + j0);
    float br[4], bi[4];
    #pragma unroll
    for (int m = 0; m < 4; ++m) {
        float gr_ = (rr[m]-mu2)*rin2*w0[m] + b0[m];
        float gi_ = (ri[m]-mu2)*rin2*w1[m] + b1[m];
        br[m] = ar[m] - xnr[m] + gr_;
        bi[m] = ai[m] - xni[m] + gi_;
    }
    store4bf(xB + base + j0, br);
    store4bf(xB + base + 1024 + j0, bi);

    s = 0.f; ss = 0.f;
    #pragma unroll
    for (int m = 0; m < 4; ++m) { s += br[m]+bi[m]; ss += br[m]*br[m] + bi[m]*bi[m]; }
    block_reduce2(s, ss, red);
    float mu3 = s * (1.f/2048.f);
    float rin3 = rsqrtf(ss * (1.f/2048.f) - mu3*mu3 + 1e-5f);

    *reinterpret_cast<float4*>(w0) = *reinterpret_cast<const float4*>(gcaw + j0);
    *reinterpret_cast<float4*>(b0) = *reinterpret_cast<const float4*>(gcab + j0);
    *reinterpret_cast<float4*>(w1) = *reinterpret_cast<const float4*>(gcaw + 1024 + j0);
    *reinterpret_cast<float4*>(b1) = *reinterpret_cast<const float4*>(gcab + 1024 + j0);
    float o0[4], o1[4];
    #pragma unroll
    for (int m = 0; m < 4; ++m) {
        o0[m] = (br[m]-mu3)*rin3*w0[m] + b0[m];
        o1[m] = (bi[m]-mu3)*rin3*w1[m] + b1[m];
    }
    store4bf(x2 + base + j0, o0);
    store4bf(x2 + base + 1024 + j0, o1);
}

// ---------- cross-attention over K=16 gist tokens: wave per (b,t) ----------
// KV combined: row (b*16+k) has Kh at [0,2048), V at [2048,4096)
__global__ __launch_bounds__(256) void attn_kernel(
    const u16* __restrict__ Q, const u16* __restrict__ KV,
    u16* __restrict__ ctx)
{
    const int wv = threadIdx.x >> 6;
    const int lane = threadIdx.x & 63;
    const int tg = blockIdx.x * 4 + wv;     // 0..8191
    const int b = tg >> 11;
    const size_t base = (size_t)tg * 2048 + lane * 32;

    float q[32];
    #pragma unroll
    for (int c = 0; c < 4; ++c)
        unpack8(*reinterpret_cast<const uint4*>(Q + base + c*8), &q[c*8]);

    float sc[16];
    #pragma unroll
    for (int k = 0; k < 16; ++k) {
        const u16* kr = KV + (size_t)(b*16 + k) * 4096 + lane*32;
        float p = 0.f;
        #pragma unroll
        for (int c = 0; c < 4; ++c) {
            float kv8[8]; unpack8(*reinterpret_cast<const uint4*>(kr + c*8), kv8);
            #pragma unroll
            for (int e = 0; e < 8; ++e) p += q[c*8+e] * kv8[e];
        }
        sc[k] = p;
    }
    #pragma unroll
    for (int k = 0; k < 16; ++k) {
        sc[k] += __shfl_xor(sc[k], 1, 64);
        sc[k] += __shfl_xor(sc[k], 2, 64);
        sc[k] *= 0.08838834764831845f;   // 1/sqrt(128)
    }
    float m = sc[0];
    #pragma unroll
    for (int k = 1; k < 16; ++k) m = fmaxf(m, sc[k]);
    float sum = 0.f;
    #pragma unroll
    for (int k = 0; k < 16; ++k) { sc[k] = expf(sc[k]-m); sum += sc[k]; }
    const float inv = 1.f / sum;

    float o[32];
    #pragma unroll
    for (int e = 0; e < 32; ++e) o[e] = 0.f;
    #pragma unroll
    for (int k = 0; k < 16; ++k) {
        const float p = sc[k] * inv;
        const u16* vr = KV + (size_t)(b*16 + k) * 4096 + 2048 + lane*32;
        #pragma unroll
        for (int c = 0; c < 4; ++c) {
            float v8[8]; unpack8(*reinterpret_cast<const uint4*>(vr + c*8), v8);
            #pragma unroll
            for (int e = 0; e < 8; ++e) o[c*8+e] += p * v8[e];
        }
    }
    #pragma unroll
    for (int c = 0; c < 4; ++c) {
        uint4 st = { pack2(o[c*8+0],o[c*8+1]), pack2(o[c*8+2],o[c*8+3]),
                     pack2(o[c*8+4],o[c*8+5]), pack2(o[c*8+6],o[c*8+7]) };
        *reinterpret_cast<uint4*>(ctx + base + c*8) = st;
    }
}

// ---------- MFMA GEMM, XOR-swizzled LDS staging, 2-phase double-buffer ----------
// C = A(MxK,bf16) * B(NxK,bf16)^T [+addf(fp32) +addb(bf16) +biasN(fp32)]
// Staging layout unchanged from prior version (verified conflict-free):
// each 16-row x 64-B subtile is one wave gld16 issue; lane j fetches
// (row=j>>2, chunk=(j&3)^((j>>3)&3)); fragment (fr,fq) lands at slot
// 4*fr + (fq ^ ((fr>>1)&3)).
// NEW: double-buffered LDS, ONE barrier per K-step; next tile's
// global_load_lds issued BEFORE current tile's ds_read+MFMA so DMA
// latency hides under compute (T3 minimum 2-phase recipe). The barrier's
// implicit vmcnt(0) drain now lands AFTER compute, not before it.
#define BM 128
#define BN 128
#define BK 32

template<int OUTF32>
__global__ __launch_bounds__(256) void gemm_bt_kernel(
    const u16* __restrict__ A, const u16* __restrict__ B,
    void* __restrict__ Cv, const float* __restrict__ addf,
    const u16* __restrict__ addb, const float* __restrict__ biasN,
    int M, int N, int K)
{
    __shared__ u16 As[2][8*512];   // 2 buffers x 8 subtiles x 1024B
    __shared__ u16 Bs[2][8*512];

    const int tid = threadIdx.x;
    const int lane = tid & 63;
    const int wave = tid >> 6;       // 0..3
    const int wm = wave >> 1;        // 0..1
    const int wn = wave & 1;         // 0..1
    const int row0 = blockIdx.y * BM;
    const int col0 = blockIdx.x * BN;

    frag_cd acc[4][4] = {};

    // staging lane mapping (swizzled)
    const int srow   = lane >> 2;                        // 0..15
    const int schunk = (lane & 3) ^ ((lane >> 3) & 3);   // 0..3
    const int scol   = schunk * 8;                       // elems
    const int s0 = wave, s1 = wave + 4;                  // this wave's subtiles

    // clamped global row bases (loop-invariant)
    int ra0 = row0 + s0*16 + srow; if (ra0 >= M) ra0 = M - 1;
    int ra1 = row0 + s1*16 + srow; if (ra1 >= M) ra1 = M - 1;
    const u16* gA0 = A + (size_t)ra0 * K + scol;
    const u16* gA1 = A + (size_t)ra1 * K + scol;
    const u16* gB0 = B + (size_t)(col0 + s0*16 + srow) * K + scol;
    const u16* gB1 = B + (size_t)(col0 + s1*16 + srow) * K + scol;

    // fragment read slot (u16 offset within subtile), loop-invariant
    const int fr = lane & 15;
    const int fq8 = lane >> 4;
    const int fslot = (4*fr + (fq8 ^ ((fr >> 1) & 3))) * 8;

    const int nt = K / BK;

    // prologue: stage tile 0 into buffer 0
    gld16(gA0, &As[0][s0*512]);
    gld16(gA1, &As[0][s1*512]);
    gld16(gB0, &Bs[0][s0*512]);
    gld16(gB1, &Bs[0][s1*512]);
    __syncthreads();   // implicit vmcnt(0): tile 0 resident

    int cur = 0;
    for (int t = 0; t < nt; ++t) {
        // issue next tile's DMA into the other buffer (hidden under compute)
        if (t + 1 < nt) {
            const int kt = (t + 1) * BK;
            gld16(gA0 + kt, &As[cur^1][s0*512]);
            gld16(gA1 + kt, &As[cur^1][s1*512]);
            gld16(gB0 + kt, &Bs[cur^1][s0*512]);
            gld16(gB1 + kt, &Bs[cur^1][s1*512]);
        }

        frag_ab af[4], bf_[4];
        #pragma unroll
        for (int i = 0; i < 4; ++i)
            af[i] = *reinterpret_cast<const frag_ab*>(&As[cur][(wm*4 + i)*512 + fslot]);
        #pragma unroll
        for (int j = 0; j < 4; ++j)
            bf_[j] = *reinterpret_cast<const frag_ab*>(&Bs[cur][(wn*4 + j)*512 + fslot]);
        #pragma unroll
        for (int i = 0; i < 4; ++i)
            #pragma unroll
            for (int j = 0; j < 4; ++j)
                acc[i][j] = __builtin_amdgcn_mfma_f32_16x16x32_bf16(af[i], bf_[j], acc[i][j], 0, 0, 0);

        // one barrier per K-step: drains this iter's DMA (vmcnt) and all
        // lgkm ops, so next iter may read cur^1 and re-stage into cur.
        __syncthreads();
        cur ^= 1;
    }

    #pragma unroll
    for (int i = 0; i < 4; ++i) {
        #pragma unroll
        for (int j = 0; j < 4; ++j) {
            #pragma unroll
            for (int r = 0; r < 4; ++r) {
                const int grow = row0 + wm*64 + i*16 + (lane >> 4) * 4 + r;
                const int gcol = col0 + wn*64 + j*16 + (lane & 15);
                if (grow < M) {
                    const size_t idx = (size_t)grow * N + gcol;
                    float v = acc[i][j][r];
                    if (addf) v += addf[idx];
                    if (addb) v += bf2f(addb[idx]);
                    if (biasN) v += biasN[gcol];
                    if (OUTF32) reinterpret_cast<float*>(Cv)[idx] = v;
                    else        reinterpret_cast<u16*>(Cv)[idx] = f2bf(v);
                }
            }
        }
    }
}

// ---------- launch ----------
extern "C" void kernel_launch(void* const* d_in, const int* in_sizes, int n_in,
                              void* d_out, int out_size, void* d_ws, size_t ws_size,
                              hipStream_t stream)
{
    const float* x          = (const float*)d_in[0];
    const float* gist_theta = (const float*)d_in[1];
    const float* gist_mag   = (const float*)d_in[2];
    const float* gist_wts   = (const float*)d_in[3];
    const float* ln_sheaf_w = (const float*)d_in[4];
    const float* ln_sheaf_b = (const float*)d_in[5];
    const float* sheaf_th   = (const float*)d_in[6];
    const float* alpha      = (const float*)d_in[7];
    const float* corr_W     = (const float*)d_in[8];
    const float* ln_gist_w  = (const float*)d_in[9];
    const float* ln_gist_b  = (const float*)d_in[10];
    const float* strength   = (const float*)d_in[11];
    const float* gr_w       = (const float*)d_in[12];
    const float* gr_b       = (const float*)d_in[13];
    const float* gca_w      = (const float*)d_in[14];
    const float* gca_b      = (const float*)d_in[15];
    const float* Wq         = (const float*)d_in[16];
    const float* Wk         = (const float*)d_in[17];
    const float* Wv         = (const float*)d_in[18];
    const float* Wo         = (const float*)d_in[19];
    const float* up_W       = (const float*)d_in[20];
    const float* up_b       = (const float*)d_in[21];
    float* out = (float*)d_out;

    char* w = (char*)d_ws;
    const size_t BIG = (size_t)4 * 2048 * 2048 * sizeof(u16);  // 33.5 MB
    u16* wA = (u16*)(w);                 // x1 -> xA -> x2(in-place) -> ctx
    u16* wB = (u16*)(w + BIG);           // WkWv(16.8MB) -> pre -> Q
    u16* wC = (u16*)(w + 2*BIG);         // Abuf(pad) -> xB
    u16* wslot = (u16*)(w + 3*BIG);      // Bbuf(pad) / single bf16 weight (8.4 MB)
    char* small = w + 3*BIG + (size_t)2048*2048*sizeof(u16);
    float* sheaf_cs = (float*)(small);
    float* gist_cs  = (float*)(small + 32768);
    u16* repr = (u16*)(small + 65536);            // 64x2048 bf16 (256 KB)
    u16* KV   = repr + 64*2048;                   // 64x4096 bf16 (512 KB)

    const int W4 = 2048*2048/4;   // float4 groups per weight matrix
    const dim3 gBig(16, 64), gKV(32, 1), gRepr(16, 1);

    setup_kernel<<<8, 256, 0, stream>>>(sheaf_th, gist_theta, gist_mag, gist_wts,
                                        strength, sheaf_cs, gist_cs);

    // gist_repr = concat(theta,mag) @ up_W^T + up_b   (K padded to 1056)
    apad_kernel<<<64, 256, 0, stream>>>(gist_theta, gist_mag, wC);
    wpad_kernel<<<2048, 256, 0, stream>>>(up_W, wslot);
    gemm_bt_kernel<0><<<gRepr, 256, 0, stream>>>(wC, wslot, repr, nullptr, nullptr, up_b,
                                                 64, 2048, 1056);

    // KV = repr @ [Wk;Wv]^T  (one N=4096 GEMM; WkWv staged bf16 in wB)
    convert_kernel<<<4096, 256, 0, stream>>>(Wk, wB, W4);
    convert_kernel<<<4096, 256, 0, stream>>>(Wv, wB + (size_t)2048*2048, W4);
    gemm_bt_kernel<0><<<gKV, 256, 0, stream>>>(repr, wB, KV, nullptr, nullptr, nullptr,
                                               64, 4096, 2048);

    ln_kernel<<<8192, 256, 0, stream>>>(x, ln_sheaf_w, ln_sheaf_b, wA);        // x1
    sheaf_kernel<<<8192, 256, 0, stream>>>(wA, sheaf_cs, alpha, wB);           // pre

    convert_kernel<<<4096, 256, 0, stream>>>(corr_W, wslot, W4);
    gemm_bt_kernel<0><<<gBig, 256, 0, stream>>>(wB, wslot, wA, x, wB, nullptr,
                                                8192, 2048, 2048);             // xA = x + pre + pre@corr^T
    stage2_kernel<<<8192, 256, 0, stream>>>(wA, gist_cs, ln_gist_w, ln_gist_b,
                                            gr_w, gr_b, gca_w, gca_b,
                                            wC, wA);                           // xB, x2
    convert_kernel<<<4096, 256, 0, stream>>>(Wq, wslot, W4);
    gemm_bt_kernel<0><<<gBig, 256, 0, stream>>>(wA, wslot, wB, nullptr, nullptr, nullptr,
                                                8192, 2048, 2048);             // Q
    attn_kernel<<<2048, 256, 0, stream>>>(wB, KV, wA);                         // ctx
    convert_kernel<<<4096, 256, 0, stream>>>(Wo, wslot, W4);
    gemm_bt_kernel<1><<<gBig, 256, 0, stream>>>(wA, wslot, (void*)out, nullptr, wC, nullptr,
                                                8192, 2048, 2048);             // out = xB + ctx@Wo^T
}

// Round 2
// 707.333 us; speedup vs baseline: 1.2304x; 1.1711x over previous
//
#include <hip/hip_runtime.h>
#include <hip/hip_bf16.h>

typedef unsigned short u16;
typedef unsigned int   u32;

using frag_ab = __attribute__((ext_vector_type(8))) short;  // 8 bf16
using frag_cd = __attribute__((ext_vector_type(4))) float;  // 4 fp32

// ---------- bf16 helpers ----------
__device__ __forceinline__ float bf2f(u16 u) {
    union { u32 i; float f; } v; v.i = ((u32)u) << 16; return v.f;
}
__device__ __forceinline__ u16 f2bf(float f) {
    __hip_bfloat16 h = __float2bfloat16(f);
    u16 u; __builtin_memcpy(&u, &h, 2); return u;
}
__device__ __forceinline__ float lo2f(u32 u) { union { u32 i; float f; } v; v.i = u << 16; return v.f; }
__device__ __forceinline__ float hi2f(u32 u) { union { u32 i; float f; } v; v.i = u & 0xffff0000u; return v.f; }
__device__ __forceinline__ void unpack8(uint4 v, float* f) {
    f[0]=lo2f(v.x); f[1]=hi2f(v.x); f[2]=lo2f(v.y); f[3]=hi2f(v.y);
    f[4]=lo2f(v.z); f[5]=hi2f(v.z); f[6]=lo2f(v.w); f[7]=hi2f(v.w);
}
__device__ __forceinline__ void load4f(const u16* p, float* f) {
    ushort4 v = *reinterpret_cast<const ushort4*>(p);
    f[0]=bf2f(v.x); f[1]=bf2f(v.y); f[2]=bf2f(v.z); f[3]=bf2f(v.w);
}
__device__ __forceinline__ void store4bf(u16* p, const float* f) {
    ushort4 v; v.x=f2bf(f[0]); v.y=f2bf(f[1]); v.z=f2bf(f[2]); v.w=f2bf(f[3]);
    *reinterpret_cast<ushort4*>(p) = v;
}
__device__ __forceinline__ u32 pack2(float a, float b) {
    return (u32)f2bf(a) | ((u32)f2bf(b) << 16);
}

// async global->LDS DMA, 16B per lane; lds dest = wave-uniform base + lane*16
__device__ __forceinline__ void gld16(const u16* g, u16* l) {
    __builtin_amdgcn_global_load_lds(
        (const __attribute__((address_space(1))) u32*)g,
        (__attribute__((address_space(3))) u32*)l, 16, 0, 0);
}

// ---------- block reduction (256 threads = 4 waves) ----------
__device__ __forceinline__ void block_reduce2(float& s, float& ss, float* red) {
    #pragma unroll
    for (int off = 32; off > 0; off >>= 1) {
        s  += __shfl_down(s, off, 64);
        ss += __shfl_down(ss, off, 64);
    }
    int wv = threadIdx.x >> 6, ln = threadIdx.x & 63;
    if (ln == 0) { red[wv*2] = s; red[wv*2+1] = ss; }
    __syncthreads();
    s  = red[0] + red[2] + red[4] + red[6];
    ss = red[1] + red[3] + red[5] + red[7];
    __syncthreads();
}

// ---------- fp32 -> bf16 conversion (n4 = n/4 float4 groups) ----------
__global__ __launch_bounds__(256) void convert_kernel(
    const float* __restrict__ in, u16* __restrict__ out, int n4)
{
    int i = blockIdx.x * 256 + threadIdx.x;
    if (i < n4) {
        float4 v = reinterpret_cast<const float4*>(in)[i];
        ushort4 o; o.x=f2bf(v.x); o.y=f2bf(v.y); o.z=f2bf(v.z); o.w=f2bf(v.w);
        reinterpret_cast<ushort4*>(out)[i] = o;
    }
}

// ---------- pad concat(theta,mag) -> Abuf (64 x 1056 bf16) ----------
__global__ __launch_bounds__(256) void apad_kernel(
    const float* __restrict__ gth, const float* __restrict__ gmag,
    u16* __restrict__ Abuf)
{
    const int r = blockIdx.x;             // 0..63
    const int tid = threadIdx.x;
    for (int c0 = tid*4; c0 < 1056; c0 += 1024) {
        float f[4];
        #pragma unroll
        for (int i = 0; i < 4; ++i) {
            int c = c0 + i;
            f[i] = (c < 1024) ? gth[(size_t)r*1024 + c] : (c == 1024 ? gmag[r] : 0.f);
        }
        store4bf(Abuf + (size_t)r*1056 + c0, f);
    }
}

// ---------- pad up_W (2048 x 1025 fp32) -> Bbuf (2048 x 1056 bf16) ----------
__global__ __launch_bounds__(256) void wpad_kernel(
    const float* __restrict__ upW, u16* __restrict__ Bbuf)
{
    const int r = blockIdx.x;             // 0..2047
    const int tid = threadIdx.x;
    for (int c0 = tid*4; c0 < 1056; c0 += 1024) {
        float f[4];
        #pragma unroll
        for (int i = 0; i < 4; ++i) {
            int c = c0 + i;
            f[i] = (c < 1025) ? upW[(size_t)r*1025 + c] : 0.f;
        }
        store4bf(Bbuf + (size_t)r*1056 + c0, f);
    }
}

// ---------- setup: cos/sin tables ----------
__global__ __launch_bounds__(256) void setup_kernel(
    const float* __restrict__ sheaf_th, const float* __restrict__ gth,
    const float* __restrict__ gmag, const float* __restrict__ gwts,
    const float* __restrict__ strength, float* __restrict__ sheaf_cs,
    float* __restrict__ gist_cs)
{
    int bx = blockIdx.x, tid = threadIdx.x;
    if (bx < 4) {
        for (int j = tid; j < 1024; j += 256) {
            float th = sheaf_th[bx*1024 + j];
            sheaf_cs[bx*1024 + j]        = cosf(th);
            sheaf_cs[4096 + bx*1024 + j] = sinf(th);
        }
    } else {
        int b = bx - 4;
        float w[16], wsum = 0.f;
        #pragma unroll
        for (int k = 0; k < 16; ++k) {
            w[k] = gwts[b*16+k] * gmag[b*16+k];
            wsum += w[k];
        }
        float inv = 1.f / (wsum + 1e-8f);
        float sig = 1.f / (1.f + expf(-strength[0]));
        for (int j = tid; j < 1024; j += 256) {
            float th = 0.f;
            #pragma unroll
            for (int k = 0; k < 16; ++k)
                th += w[k] * inv * gth[(size_t)(b*16+k)*1024 + j];
            th *= sig;
            gist_cs[b*1024 + j]        = cosf(th);
            gist_cs[4096 + b*1024 + j] = sinf(th);
        }
    }
}

// ---------- LN over rows of 2048: fp32 in -> bf16 out ----------
__global__ __launch_bounds__(256) void ln_kernel(
    const float* __restrict__ in, const float* __restrict__ w,
    const float* __restrict__ b, u16* __restrict__ out)
{
    __shared__ float red[8];
    const size_t base = (size_t)blockIdx.x * 2048;
    const int e0 = threadIdx.x * 8;
    float x[8];
    *reinterpret_cast<float4*>(&x[0]) = *reinterpret_cast<const float4*>(in + base + e0);
    *reinterpret_cast<float4*>(&x[4]) = *reinterpret_cast<const float4*>(in + base + e0 + 4);
    float s = 0.f, ss = 0.f;
    #pragma unroll
    for (int i = 0; i < 8; ++i) { s += x[i]; ss += x[i]*x[i]; }
    block_reduce2(s, ss, red);
    const float mu = s * (1.f/2048.f);
    const float rin = rsqrtf(ss * (1.f/2048.f) - mu*mu + 1e-5f);
    float wv[8], bv[8];
    *reinterpret_cast<float4*>(&wv[0]) = *reinterpret_cast<const float4*>(w + e0);
    *reinterpret_cast<float4*>(&wv[4]) = *reinterpret_cast<const float4*>(w + e0 + 4);
    *reinterpret_cast<float4*>(&bv[0]) = *reinterpret_cast<const float4*>(b + e0);
    *reinterpret_cast<float4*>(&bv[4]) = *reinterpret_cast<const float4*>(b + e0 + 4);
    float o[8];
    #pragma unroll
    for (int i = 0; i < 8; ++i) o[i] = (x[i]-mu)*rin*wv[i] + bv[i];
    uint4 st = { pack2(o[0],o[1]), pack2(o[2],o[3]), pack2(o[4],o[5]), pack2(o[6],o[7]) };
    *reinterpret_cast<uint4*>(out + base + e0) = st;
}

// ---------- sheaf: pre = x1 - |alpha| * (4*x1 - sum rot_inv(shift(x1))) ----------
__global__ __launch_bounds__(256) void sheaf_kernel(
    const u16* __restrict__ x1, const float* __restrict__ scs,
    const float* __restrict__ alpha_p, u16* __restrict__ pre)
{
    const int row = blockIdx.x;
    const int t = row & 2047;
    const int j0 = threadIdx.x * 4;
    const size_t base = (size_t)row * 2048;
    const float a = fabsf(alpha_p[0]);

    float xr[4], xi[4];
    load4f(x1 + base + j0, xr);
    load4f(x1 + base + 1024 + j0, xi);
    float lr[4], li[4];
    #pragma unroll
    for (int m = 0; m < 4; ++m) { lr[m] = 4.f*xr[m]; li[m] = 4.f*xi[m]; }

    #pragma unroll
    for (int idx = 0; idx < 4; ++idx) {
        const int sh = 3 - idx;
        if (t >= sh) {
            const float4 c4 = *reinterpret_cast<const float4*>(&scs[idx*1024 + j0]);
            const float4 s4 = *reinterpret_cast<const float4*>(&scs[4096 + idx*1024 + j0]);
            float c[4] = {c4.x, c4.y, c4.z, c4.w};
            float sn[4] = {s4.x, s4.y, s4.z, s4.w};
            float yr[4], yi[4];
            load4f(x1 + base - (size_t)sh*2048 + j0, yr);
            load4f(x1 + base - (size_t)sh*2048 + 1024 + j0, yi);
            #pragma unroll
            for (int m = 0; m < 4; ++m) {
                lr[m] -= yr[m]*c[m] + yi[m]*sn[m];     // rot_inv real
                li[m] -= yi[m]*c[m] - yr[m]*sn[m];     // rot_inv imag
            }
        }
    }
    float pr[4], pi[4];
    #pragma unroll
    for (int m = 0; m < 4; ++m) { pr[m] = xr[m] - a*lr[m]; pi[m] = xi[m] - a*li[m]; }
    store4bf(pre + base + j0, pr);
    store4bf(pre + base + 1024 + j0, pi);
}

// ---------- stage2: xn=LN(xA); g=LN(rot(xn)); xB=xA-xn+g; x2=LN(xB) ----------
__global__ __launch_bounds__(256) void stage2_kernel(
    const u16* __restrict__ xA, const float* __restrict__ gcs,
    const float* __restrict__ lgw, const float* __restrict__ lgb,
    const float* __restrict__ grw, const float* __restrict__ grb,
    const float* __restrict__ gcaw, const float* __restrict__ gcab,
    u16* __restrict__ xB, u16* __restrict__ x2)
{
    __shared__ float red[8];
    const int row = blockIdx.x;
    const int b = row >> 11;
    const int j0 = threadIdx.x * 4;
    const size_t base = (size_t)row * 2048;

    float ar[4], ai[4];
    load4f(xA + base + j0, ar);
    load4f(xA + base + 1024 + j0, ai);

    float s = 0.f, ss = 0.f;
    #pragma unroll
    for (int m = 0; m < 4; ++m) { s += ar[m]+ai[m]; ss += ar[m]*ar[m] + ai[m]*ai[m]; }
    block_reduce2(s, ss, red);
    float mu = s * (1.f/2048.f);
    float rin = rsqrtf(ss * (1.f/2048.f) - mu*mu + 1e-5f);

    float w0[4], b0[4], w1[4], b1[4];
    *reinterpret_cast<float4*>(w0) = *reinterpret_cast<const float4*>(lgw + j0);
    *reinterpret_cast<float4*>(b0) = *reinterpret_cast<const float4*>(lgb + j0);
    *reinterpret_cast<float4*>(w1) = *reinterpret_cast<const float4*>(lgw + 1024 + j0);
    *reinterpret_cast<float4*>(b1) = *reinterpret_cast<const float4*>(lgb + 1024 + j0);
    float xnr[4], xni[4];
    #pragma unroll
    for (int m = 0; m < 4; ++m) {
        xnr[m] = (ar[m]-mu)*rin*w0[m] + b0[m];
        xni[m] = (ai[m]-mu)*rin*w1[m] + b1[m];
    }

    const float4 c4 = *reinterpret_cast<const float4*>(&gcs[b*1024 + j0]);
    const float4 s4 = *reinterpret_cast<const float4*>(&gcs[4096 + b*1024 + j0]);
    float c[4] = {c4.x, c4.y, c4.z, c4.w};
    float sn[4] = {s4.x, s4.y, s4.z, s4.w};
    float rr[4], ri[4];
    #pragma unroll
    for (int m = 0; m < 4; ++m) {
        rr[m] = xnr[m]*c[m] - xni[m]*sn[m];
        ri[m] = xnr[m]*sn[m] + xni[m]*c[m];
    }

    s = 0.f; ss = 0.f;
    #pragma unroll
    for (int m = 0; m < 4; ++m) { s += rr[m]+ri[m]; ss += rr[m]*rr[m] + ri[m]*ri[m]; }
    block_reduce2(s, ss, red);
    float mu2 = s * (1.f/2048.f);
    float rin2 = rsqrtf(ss * (1.f/2048.f) - mu2*mu2 + 1e-5f);

    *reinterpret_cast<float4*>(w0) = *reinterpret_cast<const float4*>(grw + j0);
    *reinterpret_cast<float4*>(b0) = *reinterpret_cast<const float4*>(grb + j0);
    *reinterpret_cast<float4*>(w1) = *reinterpret_cast<const float4*>(grw + 1024 + j0);
    *reinterpret_cast<float4*>(b1) = *reinterpret_cast<const float4*>(grb + 1024 + j0);
    float br[4], bi[4];
    #pragma unroll
    for (int m = 0; m < 4; ++m) {
        float gr_ = (rr[m]-mu2)*rin2*w0[m] + b0[m];
        float gi_ = (ri[m]-mu2)*rin2*w1[m] + b1[m];
        br[m] = ar[m] - xnr[m] + gr_;
        bi[m] = ai[m] - xni[m] + gi_;
    }
    store4bf(xB + base + j0, br);
    store4bf(xB + base + 1024 + j0, bi);

    s = 0.f; ss = 0.f;
    #pragma unroll
    for (int m = 0; m < 4; ++m) { s += br[m]+bi[m]; ss += br[m]*br[m] + bi[m]*bi[m]; }
    block_reduce2(s, ss, red);
    float mu3 = s * (1.f/2048.f);
    float rin3 = rsqrtf(ss * (1.f/2048.f) - mu3*mu3 + 1e-5f);

    *reinterpret_cast<float4*>(w0) = *reinterpret_cast<const float4*>(gcaw + j0);
    *reinterpret_cast<float4*>(b0) = *reinterpret_cast<const float4*>(gcab + j0);
    *reinterpret_cast<float4*>(w1) = *reinterpret_cast<const float4*>(gcaw + 1024 + j0);
    *reinterpret_cast<float4*>(b1) = *reinterpret_cast<const float4*>(gcab + 1024 + j0);
    float o0[4], o1[4];
    #pragma unroll
    for (int m = 0; m < 4; ++m) {
        o0[m] = (br[m]-mu3)*rin3*w0[m] + b0[m];
        o1[m] = (bi[m]-mu3)*rin3*w1[m] + b1[m];
    }
    store4bf(x2 + base + j0, o0);
    store4bf(x2 + base + 1024 + j0, o1);
}

// ---------- cross-attention over K=16 gist tokens: wave per (b,t) ----------
// KV combined: row (b*16+k) has Kh at [0,2048), V at [2048,4096)
__global__ __launch_bounds__(256) void attn_kernel(
    const u16* __restrict__ Q, const u16* __restrict__ KV,
    u16* __restrict__ ctx)
{
    const int wv = threadIdx.x >> 6;
    const int lane = threadIdx.x & 63;
    const int tg = blockIdx.x * 4 + wv;     // 0..8191
    const int b = tg >> 11;
    const size_t base = (size_t)tg * 2048 + lane * 32;

    float q[32];
    #pragma unroll
    for (int c = 0; c < 4; ++c)
        unpack8(*reinterpret_cast<const uint4*>(Q + base + c*8), &q[c*8]);

    float sc[16];
    #pragma unroll
    for (int k = 0; k < 16; ++k) {
        const u16* kr = KV + (size_t)(b*16 + k) * 4096 + lane*32;
        float p = 0.f;
        #pragma unroll
        for (int c = 0; c < 4; ++c) {
            float kv8[8]; unpack8(*reinterpret_cast<const uint4*>(kr + c*8), kv8);
            #pragma unroll
            for (int e = 0; e < 8; ++e) p += q[c*8+e] * kv8[e];
        }
        sc[k] = p;
    }
    #pragma unroll
    for (int k = 0; k < 16; ++k) {
        sc[k] += __shfl_xor(sc[k], 1, 64);
        sc[k] += __shfl_xor(sc[k], 2, 64);
        sc[k] *= 0.08838834764831845f;   // 1/sqrt(128)
    }
    float m = sc[0];
    #pragma unroll
    for (int k = 1; k < 16; ++k) m = fmaxf(m, sc[k]);
    float sum = 0.f;
    #pragma unroll
    for (int k = 0; k < 16; ++k) { sc[k] = expf(sc[k]-m); sum += sc[k]; }
    const float inv = 1.f / sum;

    float o[32];
    #pragma unroll
    for (int e = 0; e < 32; ++e) o[e] = 0.f;
    #pragma unroll
    for (int k = 0; k < 16; ++k) {
        const float p = sc[k] * inv;
        const u16* vr = KV + (size_t)(b*16 + k) * 4096 + 2048 + lane*32;
        #pragma unroll
        for (int c = 0; c < 4; ++c) {
            float v8[8]; unpack8(*reinterpret_cast<const uint4*>(vr + c*8), v8);
            #pragma unroll
            for (int e = 0; e < 8; ++e) o[c*8+e] += p * v8[e];
        }
    }
    #pragma unroll
    for (int c = 0; c < 4; ++c) {
        uint4 st = { pack2(o[c*8+0],o[c*8+1]), pack2(o[c*8+2],o[c*8+3]),
                     pack2(o[c*8+4],o[c*8+5]), pack2(o[c*8+6],o[c*8+7]) };
        *reinterpret_cast<uint4*>(ctx + base + c*8) = st;
    }
}

// ---------- small-shape MFMA GEMM (128x128 tile, 2-phase dbuf) ----------
// kept for M=64 GEMMs (repr, KV); C = A*B^T with optional fused adds
#define BM 128
#define BN 128
#define BK 32

template<int OUTF32>
__global__ __launch_bounds__(256) void gemm_bt_kernel(
    const u16* __restrict__ A, const u16* __restrict__ B,
    void* __restrict__ Cv, const float* __restrict__ addf,
    const u16* __restrict__ addb, const float* __restrict__ biasN,
    int M, int N, int K)
{
    __shared__ u16 As[2][8*512];
    __shared__ u16 Bs[2][8*512];

    const int tid = threadIdx.x;
    const int lane = tid & 63;
    const int wave = tid >> 6;       // 0..3
    const int wm = wave >> 1;        // 0..1
    const int wn = wave & 1;         // 0..1
    const int row0 = blockIdx.y * BM;
    const int col0 = blockIdx.x * BN;

    frag_cd acc[4][4] = {};

    const int srow   = lane >> 2;
    const int schunk = (lane & 3) ^ ((lane >> 3) & 3);
    const int scol   = schunk * 8;
    const int s0 = wave, s1 = wave + 4;

    int ra0 = row0 + s0*16 + srow; if (ra0 >= M) ra0 = M - 1;
    int ra1 = row0 + s1*16 + srow; if (ra1 >= M) ra1 = M - 1;
    const u16* gA0 = A + (size_t)ra0 * K + scol;
    const u16* gA1 = A + (size_t)ra1 * K + scol;
    const u16* gB0 = B + (size_t)(col0 + s0*16 + srow) * K + scol;
    const u16* gB1 = B + (size_t)(col0 + s1*16 + srow) * K + scol;

    const int fr = lane & 15;
    const int fq8 = lane >> 4;
    const int fslot = (4*fr + (fq8 ^ ((fr >> 1) & 3))) * 8;

    const int nt = K / BK;

    gld16(gA0, &As[0][s0*512]);
    gld16(gA1, &As[0][s1*512]);
    gld16(gB0, &Bs[0][s0*512]);
    gld16(gB1, &Bs[0][s1*512]);
    __syncthreads();

    int cur = 0;
    for (int t = 0; t < nt; ++t) {
        if (t + 1 < nt) {
            const int kt = (t + 1) * BK;
            gld16(gA0 + kt, &As[cur^1][s0*512]);
            gld16(gA1 + kt, &As[cur^1][s1*512]);
            gld16(gB0 + kt, &Bs[cur^1][s0*512]);
            gld16(gB1 + kt, &Bs[cur^1][s1*512]);
        }

        frag_ab af[4], bf_[4];
        #pragma unroll
        for (int i = 0; i < 4; ++i)
            af[i] = *reinterpret_cast<const frag_ab*>(&As[cur][(wm*4 + i)*512 + fslot]);
        #pragma unroll
        for (int j = 0; j < 4; ++j)
            bf_[j] = *reinterpret_cast<const frag_ab*>(&Bs[cur][(wn*4 + j)*512 + fslot]);
        #pragma unroll
        for (int i = 0; i < 4; ++i)
            #pragma unroll
            for (int j = 0; j < 4; ++j)
                acc[i][j] = __builtin_amdgcn_mfma_f32_16x16x32_bf16(af[i], bf_[j], acc[i][j], 0, 0, 0);

        __syncthreads();
        cur ^= 1;
    }

    #pragma unroll
    for (int i = 0; i < 4; ++i) {
        #pragma unroll
        for (int j = 0; j < 4; ++j) {
            #pragma unroll
            for (int r = 0; r < 4; ++r) {
                const int grow = row0 + wm*64 + i*16 + (lane >> 4) * 4 + r;
                const int gcol = col0 + wn*64 + j*16 + (lane & 15);
                if (grow < M) {
                    const size_t idx = (size_t)grow * N + gcol;
                    float v = acc[i][j][r];
                    if (addf) v += addf[idx];
                    if (addb) v += bf2f(addb[idx]);
                    if (biasN) v += biasN[gcol];
                    if (OUTF32) reinterpret_cast<float*>(Cv)[idx] = v;
                    else        reinterpret_cast<u16*>(Cv)[idx] = f2bf(v);
                }
            }
        }
    }
}

// ---------- big MFMA GEMM: 256x256 tile, BK=64, 8-phase counted-vmcnt ----------
// 512 thr = 8 waves (2M x 4N); per-wave output 128x64 (acc[8][4]).
// LDS 128 KiB = 2buf x {A,B} x 2halves x 16 subtiles x 1024B.
// Subtile = 16 rows x 32 K bf16, staged by one wave-issue of gld16 with the
// verified lane swizzle (lane j: row=j>>2, chunk=(j&3)^((j>>3)&3));
// fragment read at fslot = (4*fr + (fq8^((fr>>1)&3)))*8.
// Schedule per iteration (2 K-tiles t0=2i[buf0], t1=2i+1[buf1], 8 phases):
//   ph0: stage A(t1)h0   ph1: A(t1)h1   ph2: B(t+2)h0  ph3: B(t+2)h1 +vmcnt(4)
//   ph4: A(t+2)h0        ph5: A(t+2)h1  ph6: B(t+3)h0  ph7: B(t+3)h1 +vmcnt(4)
// Each phase: {dsread A-quad (+all B at q==0); stage; [wait]; barrier;
//   lgkmcnt(0); sched_barrier; setprio(1); 16 MFMA; setprio(0); barrier}.
// vmcnt(4) at ph3 covers exactly tile t1's 4 half-tiles (read ph4-7);
// at ph7 covers tile t+2's (read next iter ph0-3). Loads never drain to 0.
// Requires M%? handled by clamp, N%256==0, K%128==0.
template<int OUTF32>
__global__ __launch_bounds__(512, 2) void gemm256_kernel(
    const u16* __restrict__ A, const u16* __restrict__ B,
    void* __restrict__ Cv, const float* __restrict__ addf,
    const u16* __restrict__ addb, const float* __restrict__ biasN,
    int M, int N, int K)
{
    extern __shared__ u16 lds[];            // 131072 B
    u16* Abase = lds;                       // [buf*2+half]*8192 u16
    u16* Bbase = lds + 32768;

    const int tid  = threadIdx.x;
    const int lane = tid & 63;
    const int wave = tid >> 6;              // 0..7
    const int wm   = wave >> 2;             // 0..1
    const int wn   = wave & 3;              // 0..3
    const int row0 = blockIdx.y * 256;
    const int col0 = blockIdx.x * 256;

    // staging lane mapping (verified swizzle)
    const int srow = lane >> 2;
    const int scol = ((lane & 3) ^ ((lane >> 3) & 3)) * 8;

    // per-thread stage source bases; each wave stages row-block rb=wave of a half
    int rA0 = row0 +       wave*16 + srow; if (rA0 >= M) rA0 = M - 1;
    int rA1 = row0 + 128 + wave*16 + srow; if (rA1 >= M) rA1 = M - 1;
    const u16* pA0 = A + (size_t)rA0 * K + scol;
    const u16* pA1 = A + (size_t)rA1 * K + scol;
    const u16* pB0 = B + (size_t)(col0 +       wave*16 + srow) * K + scol;
    const u16* pB1 = B + (size_t)(col0 + 128 + wave*16 + srow) * K + scol;

    const int ldsW = wave * 2 * 512;        // wave's subtile pair (u16)

    // fragment read slot
    const int fr = lane & 15;
    const int fq8 = lane >> 4;
    const int fslot = (4*fr + (fq8 ^ ((fr >> 1) & 3))) * 8;

    frag_cd acc[8][4] = {};
    frag_ab bfr[4][2];

#define STAGE256(SRC, DSTOFF, KT)                                   \
    gld16((SRC) + (KT),      (DSTOFF) + ldsW);                      \
    gld16((SRC) + (KT) + 32, (DSTOFF) + ldsW + 512);

    // prologue: B(t0)h0, B(t0)h1, A(t0)h0, A(t0)h1, B(t1)h0, B(t1)h1
    STAGE256(pB0, Bbase + 0*8192, 0);
    STAGE256(pB1, Bbase + 1*8192, 0);
    STAGE256(pA0, Abase + 0*8192, 0);
    STAGE256(pA1, Abase + 1*8192, 0);
    STAGE256(pB0, Bbase + 2*8192, 64);
    STAGE256(pB1, Bbase + 3*8192, 64);
    asm volatile("s_waitcnt vmcnt(4)" ::: "memory");   // tile0 resident
    __builtin_amdgcn_s_barrier();
    asm volatile("" ::: "memory");

    const int NI = K >> 7;                  // K/128, tiles processed in pairs
    for (int i = 0; i < NI; ++i) {
        const int t1k = i*128 + 64;
        int t2k = i*128 + 128; if (t2k >= K) t2k = K - 64;  // last-iter garbage (unread)
        int t3k = i*128 + 192; if (t3k >= K) t3k = K - 64;

        #pragma unroll
        for (int p = 0; p < 8; ++p) {
            const int q = p & 3;
            const int bufc = p >> 2;

            if (q == 0) {                   // all 8 B-frags for this K-tile
                const u16* Bh = Bbase + (bufc*2 + (wn >> 1))*8192;
                #pragma unroll
                for (int n = 0; n < 4; ++n)
                    #pragma unroll
                    for (int ks = 0; ks < 2; ++ks)
                        bfr[n][ks] = *reinterpret_cast<const frag_ab*>(
                            Bh + (((wn & 1)*4 + n)*2 + ks)*512 + fslot);
            }
            frag_ab afr[2][2];
            const u16* Ah = Abase + (bufc*2 + wm)*8192;
            #pragma unroll
            for (int r = 0; r < 2; ++r)
                #pragma unroll
                for (int ks = 0; ks < 2; ++ks)
                    afr[r][ks] = *reinterpret_cast<const frag_ab*>(
                        Ah + ((2*q + r)*2 + ks)*512 + fslot);

            switch (p) {
                case 0: STAGE256(pA0, Abase + 2*8192, t1k); break;
                case 1: STAGE256(pA1, Abase + 3*8192, t1k); break;
                case 2: STAGE256(pB0, Bbase + 0*8192, t2k); break;
                case 3: STAGE256(pB1, Bbase + 1*8192, t2k); break;
                case 4: STAGE256(pA0, Abase + 0*8192, t2k); break;
                case 5: STAGE256(pA1, Abase + 1*8192, t2k); break;
                case 6: STAGE256(pB0, Bbase + 2*8192, t3k); break;
                case 7: STAGE256(pB1, Bbase + 3*8192, t3k); break;
            }
            if (q == 3) asm volatile("s_waitcnt vmcnt(4)" ::: "memory");
            asm volatile("" ::: "memory");
            __builtin_amdgcn_s_barrier();
            asm volatile("s_waitcnt lgkmcnt(0)" ::: "memory");
            __builtin_amdgcn_sched_barrier(0);
            __builtin_amdgcn_s_setprio(1);
            #pragma unroll
            for (int r = 0; r < 2; ++r)
                #pragma unroll
                for (int n = 0; n < 4; ++n) {
                    acc[2*q + r][n] = __builtin_amdgcn_mfma_f32_16x16x32_bf16(
                        afr[r][0], bfr[n][0], acc[2*q + r][n], 0, 0, 0);
                    acc[2*q + r][n] = __builtin_amdgcn_mfma_f32_16x16x32_bf16(
                        afr[r][1], bfr[n][1], acc[2*q + r][n], 0, 0, 0);
                }
            __builtin_amdgcn_s_setprio(0);
            __builtin_amdgcn_sched_barrier(0);
            asm volatile("" ::: "memory");
            __builtin_amdgcn_s_barrier();
            asm volatile("" ::: "memory");
        }
    }
    asm volatile("s_waitcnt vmcnt(0)" ::: "memory");   // drain pending LDS DMA
#undef STAGE256

    #pragma unroll
    for (int m = 0; m < 8; ++m) {
        #pragma unroll
        for (int n = 0; n < 4; ++n) {
            #pragma unroll
            for (int r = 0; r < 4; ++r) {
                const int grow = row0 + wm*128 + m*16 + (lane >> 4) * 4 + r;
                const int gcol = col0 + wn*64 + n*16 + (lane & 15);
                if (grow < M) {
                    const size_t idx = (size_t)grow * N + gcol;
                    float v = acc[m][n][r];
                    if (addf) v += addf[idx];
                    if (addb) v += bf2f(addb[idx]);
                    if (biasN) v += biasN[gcol];
                    if (OUTF32) reinterpret_cast<float*>(Cv)[idx] = v;
                    else        reinterpret_cast<u16*>(Cv)[idx] = f2bf(v);
                }
            }
        }
    }
}

// ---------- launch ----------
extern "C" void kernel_launch(void* const* d_in, const int* in_sizes, int n_in,
                              void* d_out, int out_size, void* d_ws, size_t ws_size,
                              hipStream_t stream)
{
    const float* x          = (const float*)d_in[0];
    const float* gist_theta = (const float*)d_in[1];
    const float* gist_mag   = (const float*)d_in[2];
    const float* gist_wts   = (const float*)d_in[3];
    const float* ln_sheaf_w = (const float*)d_in[4];
    const float* ln_sheaf_b = (const float*)d_in[5];
    const float* sheaf_th   = (const float*)d_in[6];
    const float* alpha      = (const float*)d_in[7];
    const float* corr_W     = (const float*)d_in[8];
    const float* ln_gist_w  = (const float*)d_in[9];
    const float* ln_gist_b  = (const float*)d_in[10];
    const float* strength   = (const float*)d_in[11];
    const float* gr_w       = (const float*)d_in[12];
    const float* gr_b       = (const float*)d_in[13];
    const float* gca_w      = (const float*)d_in[14];
    const float* gca_b      = (const float*)d_in[15];
    const float* Wq         = (const float*)d_in[16];
    const float* Wk         = (const float*)d_in[17];
    const float* Wv         = (const float*)d_in[18];
    const float* Wo         = (const float*)d_in[19];
    const float* up_W       = (const float*)d_in[20];
    const float* up_b       = (const float*)d_in[21];
    float* out = (float*)d_out;

    static bool attr_done = false;
    if (!attr_done) {
        hipFuncSetAttribute((const void*)&gemm256_kernel<0>,
                            hipFuncAttributeMaxDynamicSharedMemorySize, 131072);
        hipFuncSetAttribute((const void*)&gemm256_kernel<1>,
                            hipFuncAttributeMaxDynamicSharedMemorySize, 131072);
        attr_done = true;
    }

    char* w = (char*)d_ws;
    const size_t BIG = (size_t)4 * 2048 * 2048 * sizeof(u16);  // 33.5 MB
    u16* wA = (u16*)(w);                 // x1 -> xA -> x2(in-place) -> ctx
    u16* wB = (u16*)(w + BIG);           // WkWv(16.8MB) -> pre -> Q
    u16* wC = (u16*)(w + 2*BIG);         // Abuf(pad) -> xB
    u16* wslot = (u16*)(w + 3*BIG);      // Bbuf(pad) / single bf16 weight (8.4 MB)
    char* small = w + 3*BIG + (size_t)2048*2048*sizeof(u16);
    float* sheaf_cs = (float*)(small);
    float* gist_cs  = (float*)(small + 32768);
    u16* repr = (u16*)(small + 65536);            // 64x2048 bf16 (256 KB)
    u16* KV   = repr + 64*2048;                   // 64x4096 bf16 (512 KB)

    const int W4 = 2048*2048/4;   // float4 groups per weight matrix
    const dim3 gBig256(2048/256, 8192/256), gKV(32, 1), gRepr(16, 1);

    setup_kernel<<<8, 256, 0, stream>>>(sheaf_th, gist_theta, gist_mag, gist_wts,
                                        strength, sheaf_cs, gist_cs);

    // gist_repr = concat(theta,mag) @ up_W^T + up_b   (K padded to 1056)
    apad_kernel<<<64, 256, 0, stream>>>(gist_theta, gist_mag, wC);
    wpad_kernel<<<2048, 256, 0, stream>>>(up_W, wslot);
    gemm_bt_kernel<0><<<gRepr, 256, 0, stream>>>(wC, wslot, repr, nullptr, nullptr, up_b,
                                                 64, 2048, 1056);

    // KV = repr @ [Wk;Wv]^T  (one N=4096 GEMM; WkWv staged bf16 in wB)
    convert_kernel<<<4096, 256, 0, stream>>>(Wk, wB, W4);
    convert_kernel<<<4096, 256, 0, stream>>>(Wv, wB + (size_t)2048*2048, W4);
    gemm_bt_kernel<0><<<gKV, 256, 0, stream>>>(repr, wB, KV, nullptr, nullptr, nullptr,
                                               64, 4096, 2048);

    ln_kernel<<<8192, 256, 0, stream>>>(x, ln_sheaf_w, ln_sheaf_b, wA);        // x1
    sheaf_kernel<<<8192, 256, 0, stream>>>(wA, sheaf_cs, alpha, wB);           // pre

    convert_kernel<<<4096, 256, 0, stream>>>(corr_W, wslot, W4);
    gemm256_kernel<0><<<gBig256, 512, 131072, stream>>>(wB, wslot, wA, x, wB, nullptr,
                                                8192, 2048, 2048);             // xA = x + pre + pre@corr^T
    stage2_kernel<<<8192, 256, 0, stream>>>(wA, gist_cs, ln_gist_w, ln_gist_b,
                                            gr_w, gr_b, gca_w, gca_b,
                                            wC, wA);                           // xB, x2
    convert_kernel<<<4096, 256, 0, stream>>>(Wq, wslot, W4);
    gemm256_kernel<0><<<gBig256, 512, 131072, stream>>>(wA, wslot, wB, nullptr, nullptr, nullptr,
                                                8192, 2048, 2048);             // Q
    attn_kernel<<<2048, 256, 0, stream>>>(wB, KV, wA);                         // ctx
    convert_kernel<<<4096, 256, 0, stream>>>(Wo, wslot, W4);
    gemm256_kernel<1><<<gBig256, 512, 131072, stream>>>(wA, wslot, (void*)out, nullptr, wC, nullptr,
                                                8192, 2048, 2048);             // out = xB + ctx@Wo^T
}

// Round 3
// 702.209 us; speedup vs baseline: 1.2394x; 1.0073x over previous
//
#include <hip/hip_runtime.h>
#include <hip/hip_bf16.h>

typedef unsigned short u16;
typedef unsigned int   u32;

using frag_ab = __attribute__((ext_vector_type(8))) short;  // 8 bf16
using frag_cd = __attribute__((ext_vector_type(4))) float;  // 4 fp32

// ---------- bf16 helpers ----------
__device__ __forceinline__ float bf2f(u16 u) {
    union { u32 i; float f; } v; v.i = ((u32)u) << 16; return v.f;
}
__device__ __forceinline__ u16 f2bf(float f) {
    __hip_bfloat16 h = __float2bfloat16(f);
    u16 u; __builtin_memcpy(&u, &h, 2); return u;
}
__device__ __forceinline__ float lo2f(u32 u) { union { u32 i; float f; } v; v.i = u << 16; return v.f; }
__device__ __forceinline__ float hi2f(u32 u) { union { u32 i; float f; } v; v.i = u & 0xffff0000u; return v.f; }
__device__ __forceinline__ void unpack8(uint4 v, float* f) {
    f[0]=lo2f(v.x); f[1]=hi2f(v.x); f[2]=lo2f(v.y); f[3]=hi2f(v.y);
    f[4]=lo2f(v.z); f[5]=hi2f(v.z); f[6]=lo2f(v.w); f[7]=hi2f(v.w);
}
__device__ __forceinline__ void load4f(const u16* p, float* f) {
    ushort4 v = *reinterpret_cast<const ushort4*>(p);
    f[0]=bf2f(v.x); f[1]=bf2f(v.y); f[2]=bf2f(v.z); f[3]=bf2f(v.w);
}
__device__ __forceinline__ void store4bf(u16* p, const float* f) {
    ushort4 v; v.x=f2bf(f[0]); v.y=f2bf(f[1]); v.z=f2bf(f[2]); v.w=f2bf(f[3]);
    *reinterpret_cast<ushort4*>(p) = v;
}
__device__ __forceinline__ u32 pack2(float a, float b) {
    return (u32)f2bf(a) | ((u32)f2bf(b) << 16);
}

// async global->LDS DMA, 16B per lane; lds dest = wave-uniform base + lane*16
__device__ __forceinline__ void gld16(const u16* g, u16* l) {
    __builtin_amdgcn_global_load_lds(
        (const __attribute__((address_space(1))) u32*)g,
        (__attribute__((address_space(3))) u32*)l, 16, 0, 0);
}

// ---------- block reduction (256 threads = 4 waves) ----------
__device__ __forceinline__ void block_reduce2(float& s, float& ss, float* red) {
    #pragma unroll
    for (int off = 32; off > 0; off >>= 1) {
        s  += __shfl_down(s, off, 64);
        ss += __shfl_down(ss, off, 64);
    }
    int wv = threadIdx.x >> 6, ln = threadIdx.x & 63;
    if (ln == 0) { red[wv*2] = s; red[wv*2+1] = ss; }
    __syncthreads();
    s  = red[0] + red[2] + red[4] + red[6];
    ss = red[1] + red[3] + red[5] + red[7];
    __syncthreads();
}

// ---------- fp32 -> bf16 conversion (n4 = n/4 float4 groups) ----------
__global__ __launch_bounds__(256) void convert_kernel(
    const float* __restrict__ in, u16* __restrict__ out, int n4)
{
    int i = blockIdx.x * 256 + threadIdx.x;
    if (i < n4) {
        float4 v = reinterpret_cast<const float4*>(in)[i];
        ushort4 o; o.x=f2bf(v.x); o.y=f2bf(v.y); o.z=f2bf(v.z); o.w=f2bf(v.w);
        reinterpret_cast<ushort4*>(out)[i] = o;
    }
}

// ---------- pad concat(theta,mag) -> Abuf (64 x 1056 bf16) ----------
__global__ __launch_bounds__(256) void apad_kernel(
    const float* __restrict__ gth, const float* __restrict__ gmag,
    u16* __restrict__ Abuf)
{
    const int r = blockIdx.x;             // 0..63
    const int tid = threadIdx.x;
    for (int c0 = tid*4; c0 < 1056; c0 += 1024) {
        float f[4];
        #pragma unroll
        for (int i = 0; i < 4; ++i) {
            int c = c0 + i;
            f[i] = (c < 1024) ? gth[(size_t)r*1024 + c] : (c == 1024 ? gmag[r] : 0.f);
        }
        store4bf(Abuf + (size_t)r*1056 + c0, f);
    }
}

// ---------- pad up_W (2048 x 1025 fp32) -> Bbuf (2048 x 1056 bf16) ----------
__global__ __launch_bounds__(256) void wpad_kernel(
    const float* __restrict__ upW, u16* __restrict__ Bbuf)
{
    const int r = blockIdx.x;             // 0..2047
    const int tid = threadIdx.x;
    for (int c0 = tid*4; c0 < 1056; c0 += 1024) {
        float f[4];
        #pragma unroll
        for (int i = 0; i < 4; ++i) {
            int c = c0 + i;
            f[i] = (c < 1025) ? upW[(size_t)r*1025 + c] : 0.f;
        }
        store4bf(Bbuf + (size_t)r*1056 + c0, f);
    }
}

// ---------- setup: cos/sin tables ----------
__global__ __launch_bounds__(256) void setup_kernel(
    const float* __restrict__ sheaf_th, const float* __restrict__ gth,
    const float* __restrict__ gmag, const float* __restrict__ gwts,
    const float* __restrict__ strength, float* __restrict__ sheaf_cs,
    float* __restrict__ gist_cs)
{
    int bx = blockIdx.x, tid = threadIdx.x;
    if (bx < 4) {
        for (int j = tid; j < 1024; j += 256) {
            float th = sheaf_th[bx*1024 + j];
            sheaf_cs[bx*1024 + j]        = cosf(th);
            sheaf_cs[4096 + bx*1024 + j] = sinf(th);
        }
    } else {
        int b = bx - 4;
        float w[16], wsum = 0.f;
        #pragma unroll
        for (int k = 0; k < 16; ++k) {
            w[k] = gwts[b*16+k] * gmag[b*16+k];
            wsum += w[k];
        }
        float inv = 1.f / (wsum + 1e-8f);
        float sig = 1.f / (1.f + expf(-strength[0]));
        for (int j = tid; j < 1024; j += 256) {
            float th = 0.f;
            #pragma unroll
            for (int k = 0; k < 16; ++k)
                th += w[k] * inv * gth[(size_t)(b*16+k)*1024 + j];
            th *= sig;
            gist_cs[b*1024 + j]        = cosf(th);
            gist_cs[4096 + b*1024 + j] = sinf(th);
        }
    }
}

// ---------- LN over rows of 2048: fp32 in -> bf16 out ----------
__global__ __launch_bounds__(256) void ln_kernel(
    const float* __restrict__ in, const float* __restrict__ w,
    const float* __restrict__ b, u16* __restrict__ out)
{
    __shared__ float red[8];
    const size_t base = (size_t)blockIdx.x * 2048;
    const int e0 = threadIdx.x * 8;
    float x[8];
    *reinterpret_cast<float4*>(&x[0]) = *reinterpret_cast<const float4*>(in + base + e0);
    *reinterpret_cast<float4*>(&x[4]) = *reinterpret_cast<const float4*>(in + base + e0 + 4);
    float s = 0.f, ss = 0.f;
    #pragma unroll
    for (int i = 0; i < 8; ++i) { s += x[i]; ss += x[i]*x[i]; }
    block_reduce2(s, ss, red);
    const float mu = s * (1.f/2048.f);
    const float rin = rsqrtf(ss * (1.f/2048.f) - mu*mu + 1e-5f);
    float wv[8], bv[8];
    *reinterpret_cast<float4*>(&wv[0]) = *reinterpret_cast<const float4*>(w + e0);
    *reinterpret_cast<float4*>(&wv[4]) = *reinterpret_cast<const float4*>(w + e0 + 4);
    *reinterpret_cast<float4*>(&bv[0]) = *reinterpret_cast<const float4*>(b + e0);
    *reinterpret_cast<float4*>(&bv[4]) = *reinterpret_cast<const float4*>(b + e0 + 4);
    float o[8];
    #pragma unroll
    for (int i = 0; i < 8; ++i) o[i] = (x[i]-mu)*rin*wv[i] + bv[i];
    uint4 st = { pack2(o[0],o[1]), pack2(o[2],o[3]), pack2(o[4],o[5]), pack2(o[6],o[7]) };
    *reinterpret_cast<uint4*>(out + base + e0) = st;
}

// ---------- sheaf: pre = x1 - |alpha| * (4*x1 - sum rot_inv(shift(x1))) ----------
__global__ __launch_bounds__(256) void sheaf_kernel(
    const u16* __restrict__ x1, const float* __restrict__ scs,
    const float* __restrict__ alpha_p, u16* __restrict__ pre)
{
    const int row = blockIdx.x;
    const int t = row & 2047;
    const int j0 = threadIdx.x * 4;
    const size_t base = (size_t)row * 2048;
    const float a = fabsf(alpha_p[0]);

    float xr[4], xi[4];
    load4f(x1 + base + j0, xr);
    load4f(x1 + base + 1024 + j0, xi);
    float lr[4], li[4];
    #pragma unroll
    for (int m = 0; m < 4; ++m) { lr[m] = 4.f*xr[m]; li[m] = 4.f*xi[m]; }

    #pragma unroll
    for (int idx = 0; idx < 4; ++idx) {
        const int sh = 3 - idx;
        if (t >= sh) {
            const float4 c4 = *reinterpret_cast<const float4*>(&scs[idx*1024 + j0]);
            const float4 s4 = *reinterpret_cast<const float4*>(&scs[4096 + idx*1024 + j0]);
            float c[4] = {c4.x, c4.y, c4.z, c4.w};
            float sn[4] = {s4.x, s4.y, s4.z, s4.w};
            float yr[4], yi[4];
            load4f(x1 + base - (size_t)sh*2048 + j0, yr);
            load4f(x1 + base - (size_t)sh*2048 + 1024 + j0, yi);
            #pragma unroll
            for (int m = 0; m < 4; ++m) {
                lr[m] -= yr[m]*c[m] + yi[m]*sn[m];     // rot_inv real
                li[m] -= yi[m]*c[m] - yr[m]*sn[m];     // rot_inv imag
            }
        }
    }
    float pr[4], pi[4];
    #pragma unroll
    for (int m = 0; m < 4; ++m) { pr[m] = xr[m] - a*lr[m]; pi[m] = xi[m] - a*li[m]; }
    store4bf(pre + base + j0, pr);
    store4bf(pre + base + 1024 + j0, pi);
}

// ---------- stage2: xn=LN(xA); g=LN(rot(xn)); xB=xA-xn+g; x2=LN(xB) ----------
__global__ __launch_bounds__(256) void stage2_kernel(
    const u16* __restrict__ xA, const float* __restrict__ gcs,
    const float* __restrict__ lgw, const float* __restrict__ lgb,
    const float* __restrict__ grw, const float* __restrict__ grb,
    const float* __restrict__ gcaw, const float* __restrict__ gcab,
    u16* __restrict__ xB, u16* __restrict__ x2)
{
    __shared__ float red[8];
    const int row = blockIdx.x;
    const int b = row >> 11;
    const int j0 = threadIdx.x * 4;
    const size_t base = (size_t)row * 2048;

    float ar[4], ai[4];
    load4f(xA + base + j0, ar);
    load4f(xA + base + 1024 + j0, ai);

    float s = 0.f, ss = 0.f;
    #pragma unroll
    for (int m = 0; m < 4; ++m) { s += ar[m]+ai[m]; ss += ar[m]*ar[m] + ai[m]*ai[m]; }
    block_reduce2(s, ss, red);
    float mu = s * (1.f/2048.f);
    float rin = rsqrtf(ss * (1.f/2048.f) - mu*mu + 1e-5f);

    float w0[4], b0[4], w1[4], b1[4];
    *reinterpret_cast<float4*>(w0) = *reinterpret_cast<const float4*>(lgw + j0);
    *reinterpret_cast<float4*>(b0) = *reinterpret_cast<const float4*>(lgb + j0);
    *reinterpret_cast<float4*>(w1) = *reinterpret_cast<const float4*>(lgw + 1024 + j0);
    *reinterpret_cast<float4*>(b1) = *reinterpret_cast<const float4*>(lgb + 1024 + j0);
    float xnr[4], xni[4];
    #pragma unroll
    for (int m = 0; m < 4; ++m) {
        xnr[m] = (ar[m]-mu)*rin*w0[m] + b0[m];
        xni[m] = (ai[m]-mu)*rin*w1[m] + b1[m];
    }

    const float4 c4 = *reinterpret_cast<const float4*>(&gcs[b*1024 + j0]);
    const float4 s4 = *reinterpret_cast<const float4*>(&gcs[4096 + b*1024 + j0]);
    float c[4] = {c4.x, c4.y, c4.z, c4.w};
    float sn[4] = {s4.x, s4.y, s4.z, s4.w};
    float rr[4], ri[4];
    #pragma unroll
    for (int m = 0; m < 4; ++m) {
        rr[m] = xnr[m]*c[m] - xni[m]*sn[m];
        ri[m] = xnr[m]*sn[m] + xni[m]*c[m];
    }

    s = 0.f; ss = 0.f;
    #pragma unroll
    for (int m = 0; m < 4; ++m) { s += rr[m]+ri[m]; ss += rr[m]*rr[m] + ri[m]*ri[m]; }
    block_reduce2(s, ss, red);
    float mu2 = s * (1.f/2048.f);
    float rin2 = rsqrtf(ss * (1.f/2048.f) - mu2*mu2 + 1e-5f);

    *reinterpret_cast<float4*>(w0) = *reinterpret_cast<const float4*>(grw + j0);
    *reinterpret_cast<float4*>(b0) = *reinterpret_cast<const float4*>(grb + j0);
    *reinterpret_cast<float4*>(w1) = *reinterpret_cast<const float4*>(grw + 1024 + j0);
    *reinterpret_cast<float4*>(b1) = *reinterpret_cast<const float4*>(grb + 1024 + j0);
    float br[4], bi[4];
    #pragma unroll
    for (int m = 0; m < 4; ++m) {
        float gr_ = (rr[m]-mu2)*rin2*w0[m] + b0[m];
        float gi_ = (ri[m]-mu2)*rin2*w1[m] + b1[m];
        br[m] = ar[m] - xnr[m] + gr_;
        bi[m] = ai[m] - xni[m] + gi_;
    }
    store4bf(xB + base + j0, br);
    store4bf(xB + base + 1024 + j0, bi);

    s = 0.f; ss = 0.f;
    #pragma unroll
    for (int m = 0; m < 4; ++m) { s += br[m]+bi[m]; ss += br[m]*br[m] + bi[m]*bi[m]; }
    block_reduce2(s, ss, red);
    float mu3 = s * (1.f/2048.f);
    float rin3 = rsqrtf(ss * (1.f/2048.f) - mu3*mu3 + 1e-5f);

    *reinterpret_cast<float4*>(w0) = *reinterpret_cast<const float4*>(gcaw + j0);
    *reinterpret_cast<float4*>(b0) = *reinterpret_cast<const float4*>(gcab + j0);
    *reinterpret_cast<float4*>(w1) = *reinterpret_cast<const float4*>(gcaw + 1024 + j0);
    *reinterpret_cast<float4*>(b1) = *reinterpret_cast<const float4*>(gcab + 1024 + j0);
    float o0[4], o1[4];
    #pragma unroll
    for (int m = 0; m < 4; ++m) {
        o0[m] = (br[m]-mu3)*rin3*w0[m] + b0[m];
        o1[m] = (bi[m]-mu3)*rin3*w1[m] + b1[m];
    }
    store4bf(x2 + base + j0, o0);
    store4bf(x2 + base + 1024 + j0, o1);
}

// ---------- cross-attention over K=16 gist tokens: wave per (b,t) ----------
// KV combined: row (b*16+k) has Kh at [0,2048), V at [2048,4096)
__global__ __launch_bounds__(256) void attn_kernel(
    const u16* __restrict__ Q, const u16* __restrict__ KV,
    u16* __restrict__ ctx)
{
    const int wv = threadIdx.x >> 6;
    const int lane = threadIdx.x & 63;
    const int tg = blockIdx.x * 4 + wv;     // 0..8191
    const int b = tg >> 11;
    const size_t base = (size_t)tg * 2048 + lane * 32;

    float q[32];
    #pragma unroll
    for (int c = 0; c < 4; ++c)
        unpack8(*reinterpret_cast<const uint4*>(Q + base + c*8), &q[c*8]);

    float sc[16];
    #pragma unroll
    for (int k = 0; k < 16; ++k) {
        const u16* kr = KV + (size_t)(b*16 + k) * 4096 + lane*32;
        float p = 0.f;
        #pragma unroll
        for (int c = 0; c < 4; ++c) {
            float kv8[8]; unpack8(*reinterpret_cast<const uint4*>(kr + c*8), kv8);
            #pragma unroll
            for (int e = 0; e < 8; ++e) p += q[c*8+e] * kv8[e];
        }
        sc[k] = p;
    }
    #pragma unroll
    for (int k = 0; k < 16; ++k) {
        sc[k] += __shfl_xor(sc[k], 1, 64);
        sc[k] += __shfl_xor(sc[k], 2, 64);
        sc[k] *= 0.08838834764831845f;   // 1/sqrt(128)
    }
    float m = sc[0];
    #pragma unroll
    for (int k = 1; k < 16; ++k) m = fmaxf(m, sc[k]);
    float sum = 0.f;
    #pragma unroll
    for (int k = 0; k < 16; ++k) { sc[k] = expf(sc[k]-m); sum += sc[k]; }
    const float inv = 1.f / sum;

    float o[32];
    #pragma unroll
    for (int e = 0; e < 32; ++e) o[e] = 0.f;
    #pragma unroll
    for (int k = 0; k < 16; ++k) {
        const float p = sc[k] * inv;
        const u16* vr = KV + (size_t)(b*16 + k) * 4096 + 2048 + lane*32;
        #pragma unroll
        for (int c = 0; c < 4; ++c) {
            float v8[8]; unpack8(*reinterpret_cast<const uint4*>(vr + c*8), v8);
            #pragma unroll
            for (int e = 0; e < 8; ++e) o[c*8+e] += p * v8[e];
        }
    }
    #pragma unroll
    for (int c = 0; c < 4; ++c) {
        uint4 st = { pack2(o[c*8+0],o[c*8+1]), pack2(o[c*8+2],o[c*8+3]),
                     pack2(o[c*8+4],o[c*8+5]), pack2(o[c*8+6],o[c*8+7]) };
        *reinterpret_cast<uint4*>(ctx + base + c*8) = st;
    }
}

// ---------- small-shape MFMA GEMM (128x128 tile, 2-phase dbuf) ----------
// kept for M=64 GEMMs (repr, KV); C = A*B^T with optional fused adds
#define BM 128
#define BN 128
#define BK 32

template<int OUTF32>
__global__ __launch_bounds__(256) void gemm_bt_kernel(
    const u16* __restrict__ A, const u16* __restrict__ B,
    void* __restrict__ Cv, const float* __restrict__ addf,
    const u16* __restrict__ addb, const float* __restrict__ biasN,
    int M, int N, int K)
{
    __shared__ u16 As[2][8*512];
    __shared__ u16 Bs[2][8*512];

    const int tid = threadIdx.x;
    const int lane = tid & 63;
    const int wave = tid >> 6;       // 0..3
    const int wm = wave >> 1;        // 0..1
    const int wn = wave & 1;         // 0..1
    const int row0 = blockIdx.y * BM;
    const int col0 = blockIdx.x * BN;

    frag_cd acc[4][4] = {};

    const int srow   = lane >> 2;
    const int schunk = (lane & 3) ^ ((lane >> 3) & 3);
    const int scol   = schunk * 8;
    const int s0 = wave, s1 = wave + 4;

    int ra0 = row0 + s0*16 + srow; if (ra0 >= M) ra0 = M - 1;
    int ra1 = row0 + s1*16 + srow; if (ra1 >= M) ra1 = M - 1;
    const u16* gA0 = A + (size_t)ra0 * K + scol;
    const u16* gA1 = A + (size_t)ra1 * K + scol;
    const u16* gB0 = B + (size_t)(col0 + s0*16 + srow) * K + scol;
    const u16* gB1 = B + (size_t)(col0 + s1*16 + srow) * K + scol;

    const int fr = lane & 15;
    const int fq8 = lane >> 4;
    const int fslot = (4*fr + (fq8 ^ ((fr >> 1) & 3))) * 8;

    const int nt = K / BK;

    gld16(gA0, &As[0][s0*512]);
    gld16(gA1, &As[0][s1*512]);
    gld16(gB0, &Bs[0][s0*512]);
    gld16(gB1, &Bs[0][s1*512]);
    __syncthreads();

    int cur = 0;
    for (int t = 0; t < nt; ++t) {
        if (t + 1 < nt) {
            const int kt = (t + 1) * BK;
            gld16(gA0 + kt, &As[cur^1][s0*512]);
            gld16(gA1 + kt, &As[cur^1][s1*512]);
            gld16(gB0 + kt, &Bs[cur^1][s0*512]);
            gld16(gB1 + kt, &Bs[cur^1][s1*512]);
        }

        frag_ab af[4], bf_[4];
        #pragma unroll
        for (int i = 0; i < 4; ++i)
            af[i] = *reinterpret_cast<const frag_ab*>(&As[cur][(wm*4 + i)*512 + fslot]);
        #pragma unroll
        for (int j = 0; j < 4; ++j)
            bf_[j] = *reinterpret_cast<const frag_ab*>(&Bs[cur][(wn*4 + j)*512 + fslot]);
        #pragma unroll
        for (int i = 0; i < 4; ++i)
            #pragma unroll
            for (int j = 0; j < 4; ++j)
                acc[i][j] = __builtin_amdgcn_mfma_f32_16x16x32_bf16(af[i], bf_[j], acc[i][j], 0, 0, 0);

        __syncthreads();
        cur ^= 1;
    }

    #pragma unroll
    for (int i = 0; i < 4; ++i) {
        #pragma unroll
        for (int j = 0; j < 4; ++j) {
            #pragma unroll
            for (int r = 0; r < 4; ++r) {
                const int grow = row0 + wm*64 + i*16 + (lane >> 4) * 4 + r;
                const int gcol = col0 + wn*64 + j*16 + (lane & 15);
                if (grow < M) {
                    const size_t idx = (size_t)grow * N + gcol;
                    float v = acc[i][j][r];
                    if (addf) v += addf[idx];
                    if (addb) v += bf2f(addb[idx]);
                    if (biasN) v += biasN[gcol];
                    if (OUTF32) reinterpret_cast<float*>(Cv)[idx] = v;
                    else        reinterpret_cast<u16*>(Cv)[idx] = f2bf(v);
                }
            }
        }
    }
}

// ---------- big MFMA GEMM: 256x256 tile, BK=64, 8-phase counted-vmcnt ----------
// v3: one-phase A-frag read-ahead (ds_reads issue inside the MFMA region so
// the LDS pipe drains under MFMA), trailing sched_barrier removed, ks-outer
// MFMA order. Requires M%256==0, N%256==0, K%128==0.
// 512 thr = 8 waves (2M x 4N); per-wave output 128x64 (acc[8][4]).
// LDS 128 KiB = 2buf x {A,B} x 2halves x 16 subtiles x 1024B.
// Staging lane swizzle + fslot fragment read as verified in prior rounds.
// vmcnt(4) at phases 3,7 keeps >=2 half-tiles in flight; never drains to 0.
template<int OUTF32>
__global__ __launch_bounds__(512, 2) void gemm256_kernel(
    const u16* __restrict__ A, const u16* __restrict__ B,
    void* __restrict__ Cv, const float* __restrict__ addf,
    const u16* __restrict__ addb, const float* __restrict__ biasN,
    int M, int N, int K)
{
    extern __shared__ u16 lds[];            // 131072 B
    u16* Abase = lds;                       // [buf*2+half]*8192 u16
    u16* Bbase = lds + 32768;

    const int tid  = threadIdx.x;
    const int lane = tid & 63;
    const int wave = tid >> 6;              // 0..7
    const int wm   = wave >> 2;             // 0..1
    const int wn   = wave & 3;              // 0..3
    const int row0 = blockIdx.y * 256;
    const int col0 = blockIdx.x * 256;

    // staging lane mapping (verified swizzle)
    const int srow = lane >> 2;
    const int scol = ((lane & 3) ^ ((lane >> 3) & 3)) * 8;

    // single pointer per matrix; +128-row half via uniform offset (saves VGPRs)
    const u16* pA = A + (size_t)(row0 + wave*16 + srow) * K + scol;
    const u16* pB = B + (size_t)(col0 + wave*16 + srow) * K + scol;
    const size_t h128 = (size_t)128 * K;    // uniform (SGPR)

    const int ldsW = wave * 1024;           // wave's subtile pair (u16 units)

    // fragment read slot
    const int fr = lane & 15;
    const int fq8 = lane >> 4;
    const int fslot = (4*fr + (fq8 ^ ((fr >> 1) & 3))) * 8;

    frag_cd acc[8][4] = {};
    frag_ab bfr[4][2];
    frag_ab afr[2][2][2];                   // [phase parity][r][ks]

#define STAGE256(SRC, DSTOFF, KT)                                   \
    gld16((SRC) + (KT),      (DSTOFF) + ldsW);                      \
    gld16((SRC) + (KT) + 32, (DSTOFF) + ldsW + 512);

    // prologue: B(t0)h0, B(t0)h1, A(t0)h0, A(t0)h1, B(t1)h0, B(t1)h1
    STAGE256(pB,        Bbase + 0*8192, 0);
    STAGE256(pB + h128, Bbase + 1*8192, 0);
    STAGE256(pA,        Abase + 0*8192, 0);
    STAGE256(pA + h128, Abase + 1*8192, 0);
    STAGE256(pB,        Bbase + 2*8192, 64);
    STAGE256(pB + h128, Bbase + 3*8192, 64);
    asm volatile("s_waitcnt vmcnt(4)" ::: "memory");   // tile0 resident
    __builtin_amdgcn_s_barrier();
    {   // pre-read phase-0 A-frags into afr[0]
        const u16* Ah = Abase + (0*2 + wm)*8192;
        #pragma unroll
        for (int r = 0; r < 2; ++r)
            #pragma unroll
            for (int ks = 0; ks < 2; ++ks)
                afr[0][r][ks] = *reinterpret_cast<const frag_ab*>(
                    Ah + ((r)*2*1 + (2*0 + r)*0 + ((0 + r)*2 + ks)*512 - (r)*2 + fslot));
    }

    const int NI = K >> 7;                  // K/128
    for (int i = 0; i < NI; ++i) {
        const int t1k = i*128 + 64;
        int t2k = i*128 + 128; if (t2k >= K) t2k = K - 64;  // last-iter garbage (unread)
        int t3k = i*128 + 192; if (t3k >= K) t3k = K - 64;

        #pragma unroll
        for (int p = 0; p < 8; ++p) {
            const int q = p & 3;
            const int bufc = p >> 2;

            if (q == 0) {                   // all 8 B-frags for this K-tile
                const u16* Bh = Bbase + (bufc*2 + (wn >> 1))*8192;
                #pragma unroll
                for (int n = 0; n < 4; ++n)
                    #pragma unroll
                    for (int ks = 0; ks < 2; ++ks)
                        bfr[n][ks] = *reinterpret_cast<const frag_ab*>(
                            Bh + (((wn & 1)*4 + n)*2 + ks)*512 + fslot);
            }
            switch (p) {
                case 0: STAGE256(pA,        Abase + 2*8192, t1k); break;
                case 1: STAGE256(pA + h128, Abase + 3*8192, t1k); break;
                case 2: STAGE256(pB,        Bbase + 0*8192, t2k); break;
                case 3: STAGE256(pB + h128, Bbase + 1*8192, t2k); break;
                case 4: STAGE256(pA,        Abase + 0*8192, t2k); break;
                case 5: STAGE256(pA + h128, Abase + 1*8192, t2k); break;
                case 6: STAGE256(pB,        Bbase + 2*8192, t3k); break;
                case 7: STAGE256(pB + h128, Bbase + 3*8192, t3k); break;
            }
            if (q == 3) asm volatile("s_waitcnt vmcnt(4)" ::: "memory");
            __builtin_amdgcn_s_barrier();
            asm volatile("s_waitcnt lgkmcnt(0)" ::: "memory");
            __builtin_amdgcn_sched_barrier(0);

            {   // read-ahead: next phase's A-frags into the other afr buffer
                const int qn = (q + 1) & 3;
                const int bufn = (q == 3) ? (bufc ^ 1) : bufc;
                const u16* Ah = Abase + (bufn*2 + wm)*8192;
                #pragma unroll
                for (int r = 0; r < 2; ++r)
                    #pragma unroll
                    for (int ks = 0; ks < 2; ++ks)
                        afr[(p+1)&1][r][ks] = *reinterpret_cast<const frag_ab*>(
                            Ah + ((2*qn + r)*2 + ks)*512 + fslot);
            }

            __builtin_amdgcn_s_setprio(1);
            #pragma unroll
            for (int ks = 0; ks < 2; ++ks)
                #pragma unroll
                for (int r = 0; r < 2; ++r)
                    #pragma unroll
                    for (int n = 0; n < 4; ++n)
                        acc[2*q + r][n] = __builtin_amdgcn_mfma_f32_16x16x32_bf16(
                            afr[p&1][r][ks], bfr[n][ks], acc[2*q + r][n], 0, 0, 0);
            __builtin_amdgcn_s_setprio(0);
            __builtin_amdgcn_s_barrier();
        }
    }
    asm volatile("s_waitcnt vmcnt(0)" ::: "memory");   // drain pending LDS DMA
#undef STAGE256

    #pragma unroll
    for (int m = 0; m < 8; ++m) {
        #pragma unroll
        for (int n = 0; n < 4; ++n) {
            #pragma unroll
            for (int r = 0; r < 4; ++r) {
                const int grow = row0 + wm*128 + m*16 + (lane >> 4) * 4 + r;
                const int gcol = col0 + wn*64 + n*16 + (lane & 15);
                {
                    const size_t idx = (size_t)grow * N + gcol;
                    float v = acc[m][n][r];
                    if (addf) v += addf[idx];
                    if (addb) v += bf2f(addb[idx]);
                    if (biasN) v += biasN[gcol];
                    if (OUTF32) reinterpret_cast<float*>(Cv)[idx] = v;
                    else        reinterpret_cast<u16*>(Cv)[idx] = f2bf(v);
                }
            }
        }
    }
}

// ---------- launch ----------
extern "C" void kernel_launch(void* const* d_in, const int* in_sizes, int n_in,
                              void* d_out, int out_size, void* d_ws, size_t ws_size,
                              hipStream_t stream)
{
    const float* x          = (const float*)d_in[0];
    const float* gist_theta = (const float*)d_in[1];
    const float* gist_mag   = (const float*)d_in[2];
    const float* gist_wts   = (const float*)d_in[3];
    const float* ln_sheaf_w = (const float*)d_in[4];
    const float* ln_sheaf_b = (const float*)d_in[5];
    const float* sheaf_th   = (const float*)d_in[6];
    const float* alpha      = (const float*)d_in[7];
    const float* corr_W     = (const float*)d_in[8];
    const float* ln_gist_w  = (const float*)d_in[9];
    const float* ln_gist_b  = (const float*)d_in[10];
    const float* strength   = (const float*)d_in[11];
    const float* gr_w       = (const float*)d_in[12];
    const float* gr_b       = (const float*)d_in[13];
    const float* gca_w      = (const float*)d_in[14];
    const float* gca_b      = (const float*)d_in[15];
    const float* Wq         = (const float*)d_in[16];
    const float* Wk         = (const float*)d_in[17];
    const float* Wv         = (const float*)d_in[18];
    const float* Wo         = (const float*)d_in[19];
    const float* up_W       = (const float*)d_in[20];
    const float* up_b       = (const float*)d_in[21];
    float* out = (float*)d_out;

    static bool attr_done = false;
    if (!attr_done) {
        hipFuncSetAttribute((const void*)&gemm256_kernel<0>,
                            hipFuncAttributeMaxDynamicSharedMemorySize, 131072);
        hipFuncSetAttribute((const void*)&gemm256_kernel<1>,
                            hipFuncAttributeMaxDynamicSharedMemorySize, 131072);
        attr_done = true;
    }

    char* w = (char*)d_ws;
    const size_t BIG = (size_t)4 * 2048 * 2048 * sizeof(u16);  // 33.5 MB
    u16* wA = (u16*)(w);                 // x1 -> xA -> x2(in-place) -> ctx
    u16* wB = (u16*)(w + BIG);           // WkWv(16.8MB) -> pre -> Q
    u16* wC = (u16*)(w + 2*BIG);         // Abuf(pad) -> xB
    u16* wslot = (u16*)(w + 3*BIG);      // Bbuf(pad) / single bf16 weight (8.4 MB)
    char* small = w + 3*BIG + (size_t)2048*2048*sizeof(u16);
    float* sheaf_cs = (float*)(small);
    float* gist_cs  = (float*)(small + 32768);
    u16* repr = (u16*)(small + 65536);            // 64x2048 bf16 (256 KB)
    u16* KV   = repr + 64*2048;                   // 64x4096 bf16 (512 KB)

    const int W4 = 2048*2048/4;   // float4 groups per weight matrix
    const dim3 gBig256(2048/256, 8192/256), gKV(32, 1), gRepr(16, 1);

    setup_kernel<<<8, 256, 0, stream>>>(sheaf_th, gist_theta, gist_mag, gist_wts,
                                        strength, sheaf_cs, gist_cs);

    // gist_repr = concat(theta,mag) @ up_W^T + up_b   (K padded to 1056)
    apad_kernel<<<64, 256, 0, stream>>>(gist_theta, gist_mag, wC);
    wpad_kernel<<<2048, 256, 0, stream>>>(up_W, wslot);
    gemm_bt_kernel<0><<<gRepr, 256, 0, stream>>>(wC, wslot, repr, nullptr, nullptr, up_b,
                                                 64, 2048, 1056);

    // KV = repr @ [Wk;Wv]^T  (one N=4096 GEMM; WkWv staged bf16 in wB)
    convert_kernel<<<4096, 256, 0, stream>>>(Wk, wB, W4);
    convert_kernel<<<4096, 256, 0, stream>>>(Wv, wB + (size_t)2048*2048, W4);
    gemm_bt_kernel<0><<<gKV, 256, 0, stream>>>(repr, wB, KV, nullptr, nullptr, nullptr,
                                               64, 4096, 2048);

    ln_kernel<<<8192, 256, 0, stream>>>(x, ln_sheaf_w, ln_sheaf_b, wA);        // x1
    sheaf_kernel<<<8192, 256, 0, stream>>>(wA, sheaf_cs, alpha, wB);           // pre

    convert_kernel<<<4096, 256, 0, stream>>>(corr_W, wslot, W4);
    gemm256_kernel<0><<<gBig256, 512, 131072, stream>>>(wB, wslot, wA, x, wB, nullptr,
                                                8192, 2048, 2048);             // xA = x + pre + pre@corr^T
    stage2_kernel<<<8192, 256, 0, stream>>>(wA, gist_cs, ln_gist_w, ln_gist_b,
                                            gr_w, gr_b, gca_w, gca_b,
                                            wC, wA);                           // xB, x2
    convert_kernel<<<4096, 256, 0, stream>>>(Wq, wslot, W4);
    gemm256_kernel<0><<<gBig256, 512, 131072, stream>>>(wA, wslot, wB, nullptr, nullptr, nullptr,
                                                8192, 2048, 2048);             // Q
    attn_kernel<<<2048, 256, 0, stream>>>(wB, KV, wA);                         // ctx
    convert_kernel<<<4096, 256, 0, stream>>>(Wo, wslot, W4);
    gemm256_kernel<1><<<gBig256, 512, 131072, stream>>>(wA, wslot, (void*)out, nullptr, wC, nullptr,
                                                8192, 2048, 2048);             // out = xB + ctx@Wo^T
}

// Round 4
// 647.151 us; speedup vs baseline: 1.3448x; 1.0851x over previous
//
#include <hip/hip_runtime.h>
#include <hip/hip_bf16.h>

typedef unsigned short u16;
typedef unsigned int   u32;

using frag_ab = __attribute__((ext_vector_type(8))) short;  // 8 bf16
using frag_cd = __attribute__((ext_vector_type(4))) float;  // 4 fp32

// ---------- bf16 helpers ----------
__device__ __forceinline__ float bf2f(u16 u) {
    union { u32 i; float f; } v; v.i = ((u32)u) << 16; return v.f;
}
__device__ __forceinline__ u16 f2bf(float f) {
    __hip_bfloat16 h = __float2bfloat16(f);
    u16 u; __builtin_memcpy(&u, &h, 2); return u;
}
__device__ __forceinline__ float lo2f(u32 u) { union { u32 i; float f; } v; v.i = u << 16; return v.f; }
__device__ __forceinline__ float hi2f(u32 u) { union { u32 i; float f; } v; v.i = u & 0xffff0000u; return v.f; }
__device__ __forceinline__ void unpack8(uint4 v, float* f) {
    f[0]=lo2f(v.x); f[1]=hi2f(v.x); f[2]=lo2f(v.y); f[3]=hi2f(v.y);
    f[4]=lo2f(v.z); f[5]=hi2f(v.z); f[6]=lo2f(v.w); f[7]=hi2f(v.w);
}
__device__ __forceinline__ void load4f(const u16* p, float* f) {
    ushort4 v = *reinterpret_cast<const ushort4*>(p);
    f[0]=bf2f(v.x); f[1]=bf2f(v.y); f[2]=bf2f(v.z); f[3]=bf2f(v.w);
}
__device__ __forceinline__ void store4bf(u16* p, const float* f) {
    ushort4 v; v.x=f2bf(f[0]); v.y=f2bf(f[1]); v.z=f2bf(f[2]); v.w=f2bf(f[3]);
    *reinterpret_cast<ushort4*>(p) = v;
}
__device__ __forceinline__ u32 pack2(float a, float b) {
    return (u32)f2bf(a) | ((u32)f2bf(b) << 16);
}

// async global->LDS DMA, 16B per lane; lds dest = wave-uniform base + lane*16
__device__ __forceinline__ void gld16(const u16* g, u16* l) {
    __builtin_amdgcn_global_load_lds(
        (const __attribute__((address_space(1))) u32*)g,
        (__attribute__((address_space(3))) u32*)l, 16, 0, 0);
}

// raw LDS byte address (address-space 3 offset) of a __shared__ pointer
__device__ __forceinline__ u32 ldsaddr(const u16* p) {
    return (u32)(uintptr_t)(const __attribute__((address_space(3))) u16*)p;
}

// inline-asm ds_read_b128: invisible to SIInsertWaitcnts' DMA-alias analysis;
// hazard discipline is OURS: reads pre-barrier, then s_barrier + lgkmcnt(0)
// + sched_barrier(0) before the consuming MFMAs (rule 18).
__device__ __forceinline__ frag_ab dsread16(u32 a) {
    frag_ab r;
    asm volatile("ds_read_b128 %0, %1" : "=v"(r) : "v"(a));
    return r;
}

// ---------- block reduction (256 threads = 4 waves) ----------
__device__ __forceinline__ void block_reduce2(float& s, float& ss, float* red) {
    #pragma unroll
    for (int off = 32; off > 0; off >>= 1) {
        s  += __shfl_down(s, off, 64);
        ss += __shfl_down(ss, off, 64);
    }
    int wv = threadIdx.x >> 6, ln = threadIdx.x & 63;
    if (ln == 0) { red[wv*2] = s; red[wv*2+1] = ss; }
    __syncthreads();
    s  = red[0] + red[2] + red[4] + red[6];
    ss = red[1] + red[3] + red[5] + red[7];
    __syncthreads();
}

// ---------- fp32 -> bf16 conversion (n4 = n/4 float4 groups) ----------
__global__ __launch_bounds__(256) void convert_kernel(
    const float* __restrict__ in, u16* __restrict__ out, int n4)
{
    int i = blockIdx.x * 256 + threadIdx.x;
    if (i < n4) {
        float4 v = reinterpret_cast<const float4*>(in)[i];
        ushort4 o; o.x=f2bf(v.x); o.y=f2bf(v.y); o.z=f2bf(v.z); o.w=f2bf(v.w);
        reinterpret_cast<ushort4*>(out)[i] = o;
    }
}

// ---------- pad concat(theta,mag) -> Abuf (64 x 1056 bf16) ----------
__global__ __launch_bounds__(256) void apad_kernel(
    const float* __restrict__ gth, const float* __restrict__ gmag,
    u16* __restrict__ Abuf)
{
    const int r = blockIdx.x;             // 0..63
    const int tid = threadIdx.x;
    for (int c0 = tid*4; c0 < 1056; c0 += 1024) {
        float f[4];
        #pragma unroll
        for (int i = 0; i < 4; ++i) {
            int c = c0 + i;
            f[i] = (c < 1024) ? gth[(size_t)r*1024 + c] : (c == 1024 ? gmag[r] : 0.f);
        }
        store4bf(Abuf + (size_t)r*1056 + c0, f);
    }
}

// ---------- pad up_W (2048 x 1025 fp32) -> Bbuf (2048 x 1056 bf16) ----------
__global__ __launch_bounds__(256) void wpad_kernel(
    const float* __restrict__ upW, u16* __restrict__ Bbuf)
{
    const int r = blockIdx.x;             // 0..2047
    const int tid = threadIdx.x;
    for (int c0 = tid*4; c0 < 1056; c0 += 1024) {
        float f[4];
        #pragma unroll
        for (int i = 0; i < 4; ++i) {
            int c = c0 + i;
            f[i] = (c < 1025) ? upW[(size_t)r*1025 + c] : 0.f;
        }
        store4bf(Bbuf + (size_t)r*1056 + c0, f);
    }
}

// ---------- setup: cos/sin tables ----------
__global__ __launch_bounds__(256) void setup_kernel(
    const float* __restrict__ sheaf_th, const float* __restrict__ gth,
    const float* __restrict__ gmag, const float* __restrict__ gwts,
    const float* __restrict__ strength, float* __restrict__ sheaf_cs,
    float* __restrict__ gist_cs)
{
    int bx = blockIdx.x, tid = threadIdx.x;
    if (bx < 4) {
        for (int j = tid; j < 1024; j += 256) {
            float th = sheaf_th[bx*1024 + j];
            sheaf_cs[bx*1024 + j]        = cosf(th);
            sheaf_cs[4096 + bx*1024 + j] = sinf(th);
        }
    } else {
        int b = bx - 4;
        float w[16], wsum = 0.f;
        #pragma unroll
        for (int k = 0; k < 16; ++k) {
            w[k] = gwts[b*16+k] * gmag[b*16+k];
            wsum += w[k];
        }
        float inv = 1.f / (wsum + 1e-8f);
        float sig = 1.f / (1.f + expf(-strength[0]));
        for (int j = tid; j < 1024; j += 256) {
            float th = 0.f;
            #pragma unroll
            for (int k = 0; k < 16; ++k)
                th += w[k] * inv * gth[(size_t)(b*16+k)*1024 + j];
            th *= sig;
            gist_cs[b*1024 + j]        = cosf(th);
            gist_cs[4096 + b*1024 + j] = sinf(th);
        }
    }
}

// ---------- LN over rows of 2048: fp32 in -> bf16 out ----------
__global__ __launch_bounds__(256) void ln_kernel(
    const float* __restrict__ in, const float* __restrict__ w,
    const float* __restrict__ b, u16* __restrict__ out)
{
    __shared__ float red[8];
    const size_t base = (size_t)blockIdx.x * 2048;
    const int e0 = threadIdx.x * 8;
    float x[8];
    *reinterpret_cast<float4*>(&x[0]) = *reinterpret_cast<const float4*>(in + base + e0);
    *reinterpret_cast<float4*>(&x[4]) = *reinterpret_cast<const float4*>(in + base + e0 + 4);
    float s = 0.f, ss = 0.f;
    #pragma unroll
    for (int i = 0; i < 8; ++i) { s += x[i]; ss += x[i]*x[i]; }
    block_reduce2(s, ss, red);
    const float mu = s * (1.f/2048.f);
    const float rin = rsqrtf(ss * (1.f/2048.f) - mu*mu + 1e-5f);
    float wv[8], bv[8];
    *reinterpret_cast<float4*>(&wv[0]) = *reinterpret_cast<const float4*>(w + e0);
    *reinterpret_cast<float4*>(&wv[4]) = *reinterpret_cast<const float4*>(w + e0 + 4);
    *reinterpret_cast<float4*>(&bv[0]) = *reinterpret_cast<const float4*>(b + e0);
    *reinterpret_cast<float4*>(&bv[4]) = *reinterpret_cast<const float4*>(b + e0 + 4);
    float o[8];
    #pragma unroll
    for (int i = 0; i < 8; ++i) o[i] = (x[i]-mu)*rin*wv[i] + bv[i];
    uint4 st = { pack2(o[0],o[1]), pack2(o[2],o[3]), pack2(o[4],o[5]), pack2(o[6],o[7]) };
    *reinterpret_cast<uint4*>(out + base + e0) = st;
}

// ---------- sheaf: pre = x1 - |alpha| * (4*x1 - sum rot_inv(shift(x1))) ----------
__global__ __launch_bounds__(256) void sheaf_kernel(
    const u16* __restrict__ x1, const float* __restrict__ scs,
    const float* __restrict__ alpha_p, u16* __restrict__ pre)
{
    const int row = blockIdx.x;
    const int t = row & 2047;
    const int j0 = threadIdx.x * 4;
    const size_t base = (size_t)row * 2048;
    const float a = fabsf(alpha_p[0]);

    float xr[4], xi[4];
    load4f(x1 + base + j0, xr);
    load4f(x1 + base + 1024 + j0, xi);
    float lr[4], li[4];
    #pragma unroll
    for (int m = 0; m < 4; ++m) { lr[m] = 4.f*xr[m]; li[m] = 4.f*xi[m]; }

    #pragma unroll
    for (int idx = 0; idx < 4; ++idx) {
        const int sh = 3 - idx;
        if (t >= sh) {
            const float4 c4 = *reinterpret_cast<const float4*>(&scs[idx*1024 + j0]);
            const float4 s4 = *reinterpret_cast<const float4*>(&scs[4096 + idx*1024 + j0]);
            float c[4] = {c4.x, c4.y, c4.z, c4.w};
            float sn[4] = {s4.x, s4.y, s4.z, s4.w};
            float yr[4], yi[4];
            load4f(x1 + base - (size_t)sh*2048 + j0, yr);
            load4f(x1 + base - (size_t)sh*2048 + 1024 + j0, yi);
            #pragma unroll
            for (int m = 0; m < 4; ++m) {
                lr[m] -= yr[m]*c[m] + yi[m]*sn[m];     // rot_inv real
                li[m] -= yi[m]*c[m] - yr[m]*sn[m];     // rot_inv imag
            }
        }
    }
    float pr[4], pi[4];
    #pragma unroll
    for (int m = 0; m < 4; ++m) { pr[m] = xr[m] - a*lr[m]; pi[m] = xi[m] - a*li[m]; }
    store4bf(pre + base + j0, pr);
    store4bf(pre + base + 1024 + j0, pi);
}

// ---------- stage2: xn=LN(xA); g=LN(rot(xn)); xB=xA-xn+g; x2=LN(xB) ----------
__global__ __launch_bounds__(256) void stage2_kernel(
    const u16* __restrict__ xA, const float* __restrict__ gcs,
    const float* __restrict__ lgw, const float* __restrict__ lgb,
    const float* __restrict__ grw, const float* __restrict__ grb,
    const float* __restrict__ gcaw, const float* __restrict__ gcab,
    u16* __restrict__ xB, u16* __restrict__ x2)
{
    __shared__ float red[8];
    const int row = blockIdx.x;
    const int b = row >> 11;
    const int j0 = threadIdx.x * 4;
    const size_t base = (size_t)row * 2048;

    float ar[4], ai[4];
    load4f(xA + base + j0, ar);
    load4f(xA + base + 1024 + j0, ai);

    float s = 0.f, ss = 0.f;
    #pragma unroll
    for (int m = 0; m < 4; ++m) { s += ar[m]+ai[m]; ss += ar[m]*ar[m] + ai[m]*ai[m]; }
    block_reduce2(s, ss, red);
    float mu = s * (1.f/2048.f);
    float rin = rsqrtf(ss * (1.f/2048.f) - mu*mu + 1e-5f);

    float w0[4], b0[4], w1[4], b1[4];
    *reinterpret_cast<float4*>(w0) = *reinterpret_cast<const float4*>(lgw + j0);
    *reinterpret_cast<float4*>(b0) = *reinterpret_cast<const float4*>(lgb + j0);
    *reinterpret_cast<float4*>(w1) = *reinterpret_cast<const float4*>(lgw + 1024 + j0);
    *reinterpret_cast<float4*>(b1) = *reinterpret_cast<const float4*>(lgb + 1024 + j0);
    float xnr[4], xni[4];
    #pragma unroll
    for (int m = 0; m < 4; ++m) {
        xnr[m] = (ar[m]-mu)*rin*w0[m] + b0[m];
        xni[m] = (ai[m]-mu)*rin*w1[m] + b1[m];
    }

    const float4 c4 = *reinterpret_cast<const float4*>(&gcs[b*1024 + j0]);
    const float4 s4 = *reinterpret_cast<const float4*>(&gcs[4096 + b*1024 + j0]);
    float c[4] = {c4.x, c4.y, c4.z, c4.w};
    float sn[4] = {s4.x, s4.y, s4.z, s4.w};
    float rr[4], ri[4];
    #pragma unroll
    for (int m = 0; m < 4; ++m) {
        rr[m] = xnr[m]*c[m] - xni[m]*sn[m];
        ri[m] = xnr[m]*sn[m] + xni[m]*c[m];
    }

    s = 0.f; ss = 0.f;
    #pragma unroll
    for (int m = 0; m < 4; ++m) { s += rr[m]+ri[m]; ss += rr[m]*rr[m] + ri[m]*ri[m]; }
    block_reduce2(s, ss, red);
    float mu2 = s * (1.f/2048.f);
    float rin2 = rsqrtf(ss * (1.f/2048.f) - mu2*mu2 + 1e-5f);

    *reinterpret_cast<float4*>(w0) = *reinterpret_cast<const float4*>(grw + j0);
    *reinterpret_cast<float4*>(b0) = *reinterpret_cast<const float4*>(grb + j0);
    *reinterpret_cast<float4*>(w1) = *reinterpret_cast<const float4*>(grw + 1024 + j0);
    *reinterpret_cast<float4*>(b1) = *reinterpret_cast<const float4*>(grb + 1024 + j0);
    float br[4], bi[4];
    #pragma unroll
    for (int m = 0; m < 4; ++m) {
        float gr_ = (rr[m]-mu2)*rin2*w0[m] + b0[m];
        float gi_ = (ri[m]-mu2)*rin2*w1[m] + b1[m];
        br[m] = ar[m] - xnr[m] + gr_;
        bi[m] = ai[m] - xni[m] + gi_;
    }
    store4bf(xB + base + j0, br);
    store4bf(xB + base + 1024 + j0, bi);

    s = 0.f; ss = 0.f;
    #pragma unroll
    for (int m = 0; m < 4; ++m) { s += br[m]+bi[m]; ss += br[m]*br[m] + bi[m]*bi[m]; }
    block_reduce2(s, ss, red);
    float mu3 = s * (1.f/2048.f);
    float rin3 = rsqrtf(ss * (1.f/2048.f) - mu3*mu3 + 1e-5f);

    *reinterpret_cast<float4*>(w0) = *reinterpret_cast<const float4*>(gcaw + j0);
    *reinterpret_cast<float4*>(b0) = *reinterpret_cast<const float4*>(gcab + j0);
    *reinterpret_cast<float4*>(w1) = *reinterpret_cast<const float4*>(gcaw + 1024 + j0);
    *reinterpret_cast<float4*>(b1) = *reinterpret_cast<const float4*>(gcab + 1024 + j0);
    float o0[4], o1[4];
    #pragma unroll
    for (int m = 0; m < 4; ++m) {
        o0[m] = (br[m]-mu3)*rin3*w0[m] + b0[m];
        o1[m] = (bi[m]-mu3)*rin3*w1[m] + b1[m];
    }
    store4bf(x2 + base + j0, o0);
    store4bf(x2 + base + 1024 + j0, o1);
}

// ---------- cross-attention over K=16 gist tokens: wave per (b,t) ----------
// KV combined: row (b*16+k) has Kh at [0,2048), V at [2048,4096)
__global__ __launch_bounds__(256) void attn_kernel(
    const u16* __restrict__ Q, const u16* __restrict__ KV,
    u16* __restrict__ ctx)
{
    const int wv = threadIdx.x >> 6;
    const int lane = threadIdx.x & 63;
    const int tg = blockIdx.x * 4 + wv;     // 0..8191
    const int b = tg >> 11;
    const size_t base = (size_t)tg * 2048 + lane * 32;

    float q[32];
    #pragma unroll
    for (int c = 0; c < 4; ++c)
        unpack8(*reinterpret_cast<const uint4*>(Q + base + c*8), &q[c*8]);

    float sc[16];
    #pragma unroll
    for (int k = 0; k < 16; ++k) {
        const u16* kr = KV + (size_t)(b*16 + k) * 4096 + lane*32;
        float p = 0.f;
        #pragma unroll
        for (int c = 0; c < 4; ++c) {
            float kv8[8]; unpack8(*reinterpret_cast<const uint4*>(kr + c*8), kv8);
            #pragma unroll
            for (int e = 0; e < 8; ++e) p += q[c*8+e] * kv8[e];
        }
        sc[k] = p;
    }
    #pragma unroll
    for (int k = 0; k < 16; ++k) {
        sc[k] += __shfl_xor(sc[k], 1, 64);
        sc[k] += __shfl_xor(sc[k], 2, 64);
        sc[k] *= 0.08838834764831845f;   // 1/sqrt(128)
    }
    float m = sc[0];
    #pragma unroll
    for (int k = 1; k < 16; ++k) m = fmaxf(m, sc[k]);
    float sum = 0.f;
    #pragma unroll
    for (int k = 0; k < 16; ++k) { sc[k] = expf(sc[k]-m); sum += sc[k]; }
    const float inv = 1.f / sum;

    float o[32];
    #pragma unroll
    for (int e = 0; e < 32; ++e) o[e] = 0.f;
    #pragma unroll
    for (int k = 0; k < 16; ++k) {
        const float p = sc[k] * inv;
        const u16* vr = KV + (size_t)(b*16 + k) * 4096 + 2048 + lane*32;
        #pragma unroll
        for (int c = 0; c < 4; ++c) {
            float v8[8]; unpack8(*reinterpret_cast<const uint4*>(vr + c*8), v8);
            #pragma unroll
            for (int e = 0; e < 8; ++e) o[c*8+e] += p * v8[e];
        }
    }
    #pragma unroll
    for (int c = 0; c < 4; ++c) {
        uint4 st = { pack2(o[c*8+0],o[c*8+1]), pack2(o[c*8+2],o[c*8+3]),
                     pack2(o[c*8+4],o[c*8+5]), pack2(o[c*8+6],o[c*8+7]) };
        *reinterpret_cast<uint4*>(ctx + base + c*8) = st;
    }
}

// ---------- small-shape MFMA GEMM (128x128 tile, 2-phase dbuf) ----------
// OUTMODE: 0 = bf16 out (+adds), 1 = f32 out (+adds),
//          2 = f32 partial per blockIdx.z K-chunk (no adds) for K-split
#define BM 128
#define BN 128
#define BK 32

template<int OUTMODE>
__global__ __launch_bounds__(256) void gemm_bt_kernel(
    const u16* __restrict__ A, const u16* __restrict__ B,
    void* __restrict__ Cv, const float* __restrict__ addf,
    const u16* __restrict__ addb, const float* __restrict__ biasN,
    int M, int N, int K)
{
    __shared__ u16 As[2][8*512];
    __shared__ u16 Bs[2][8*512];

    const int tid = threadIdx.x;
    const int lane = tid & 63;
    const int wave = tid >> 6;       // 0..3
    const int wm = wave >> 1;        // 0..1
    const int wn = wave & 1;         // 0..1
    const int row0 = blockIdx.y * BM;
    const int col0 = blockIdx.x * BN;

    frag_cd acc[4][4] = {};

    const int srow   = lane >> 2;
    const int schunk = (lane & 3) ^ ((lane >> 3) & 3);
    const int scol   = schunk * 8;
    const int s0 = wave, s1 = wave + 4;

    int ra0 = row0 + s0*16 + srow; if (ra0 >= M) ra0 = M - 1;
    int ra1 = row0 + s1*16 + srow; if (ra1 >= M) ra1 = M - 1;
    const u16* gA0 = A + (size_t)ra0 * K + scol;
    const u16* gA1 = A + (size_t)ra1 * K + scol;
    const u16* gB0 = B + (size_t)(col0 + s0*16 + srow) * K + scol;
    const u16* gB1 = B + (size_t)(col0 + s1*16 + srow) * K + scol;

    const int fr = lane & 15;
    const int fq8 = lane >> 4;
    const int fslot = (4*fr + (fq8 ^ ((fr >> 1) & 3))) * 8;

    const int nsteps = K / BK;
    int ts = 0, te = nsteps;
    if (OUTMODE == 2) {
        ts = (nsteps * (int)blockIdx.z) / (int)gridDim.z;
        te = (nsteps * ((int)blockIdx.z + 1)) / (int)gridDim.z;
    }

    gld16(gA0 + ts*BK, &As[0][s0*512]);
    gld16(gA1 + ts*BK, &As[0][s1*512]);
    gld16(gB0 + ts*BK, &Bs[0][s0*512]);
    gld16(gB1 + ts*BK, &Bs[0][s1*512]);
    __syncthreads();

    int cur = 0;
    for (int t = ts; t < te; ++t) {
        if (t + 1 < te) {
            const int kt = (t + 1) * BK;
            gld16(gA0 + kt, &As[cur^1][s0*512]);
            gld16(gA1 + kt, &As[cur^1][s1*512]);
            gld16(gB0 + kt, &Bs[cur^1][s0*512]);
            gld16(gB1 + kt, &Bs[cur^1][s1*512]);
        }

        frag_ab af[4], bf_[4];
        #pragma unroll
        for (int i = 0; i < 4; ++i)
            af[i] = *reinterpret_cast<const frag_ab*>(&As[cur][(wm*4 + i)*512 + fslot]);
        #pragma unroll
        for (int j = 0; j < 4; ++j)
            bf_[j] = *reinterpret_cast<const frag_ab*>(&Bs[cur][(wn*4 + j)*512 + fslot]);
        #pragma unroll
        for (int i = 0; i < 4; ++i)
            #pragma unroll
            for (int j = 0; j < 4; ++j)
                acc[i][j] = __builtin_amdgcn_mfma_f32_16x16x32_bf16(af[i], bf_[j], acc[i][j], 0, 0, 0);

        __syncthreads();
        cur ^= 1;
    }

    float* Pz = (OUTMODE == 2)
        ? reinterpret_cast<float*>(Cv) + (size_t)blockIdx.z * M * N : nullptr;

    #pragma unroll
    for (int i = 0; i < 4; ++i) {
        #pragma unroll
        for (int j = 0; j < 4; ++j) {
            #pragma unroll
            for (int r = 0; r < 4; ++r) {
                const int grow = row0 + wm*64 + i*16 + (lane >> 4) * 4 + r;
                const int gcol = col0 + wn*64 + j*16 + (lane & 15);
                if (grow < M) {
                    const size_t idx = (size_t)grow * N + gcol;
                    float v = acc[i][j][r];
                    if (OUTMODE == 2) {
                        Pz[idx] = v;
                    } else {
                        if (addf) v += addf[idx];
                        if (addb) v += bf2f(addb[idx]);
                        if (biasN) v += biasN[gcol];
                        if (OUTMODE == 1) reinterpret_cast<float*>(Cv)[idx] = v;
                        else              reinterpret_cast<u16*>(Cv)[idx] = f2bf(v);
                    }
                }
            }
        }
    }
}

// ---------- K-split reduce: sum nz fp32 partials (+optional biasN) -> bf16 ----------
__global__ __launch_bounds__(256) void ksum_kernel(
    const float* __restrict__ part, int nz, int n4, int N,
    const float* __restrict__ biasN, u16* __restrict__ out)
{
    int i = blockIdx.x * 256 + threadIdx.x;
    if (i >= n4) return;
    const float4* p4 = reinterpret_cast<const float4*>(part);
    float4 s = p4[i];
    for (int z = 1; z < nz; ++z) {
        float4 t = p4[i + (size_t)z * n4];
        s.x += t.x; s.y += t.y; s.z += t.z; s.w += t.w;
    }
    if (biasN) {
        int col = (i * 4) % N;
        s.x += biasN[col]; s.y += biasN[col+1]; s.z += biasN[col+2]; s.w += biasN[col+3];
    }
    ushort4 o; o.x=f2bf(s.x); o.y=f2bf(s.y); o.z=f2bf(s.z); o.w=f2bf(s.w);
    reinterpret_cast<ushort4*>(out)[i] = o;
}

// ---------- big MFMA GEMM: 256x256 tile, BK=64, 8-phase counted-vmcnt ----------
// v4: ALL fragment reads via inline-asm ds_read_b128 on raw AS3 addresses so
// the compiler's waitcnt inserter cannot add conservative vmcnt(0) drains for
// possible global_load_lds/LDS-read aliasing (the R2/R3 ~2190cyc/phase gate).
// Hazard protocol (ours, verified): reads at phase top (pre-barrier) of
// buffers made resident by the q3 vmcnt(4)+barrier of the prior half-iter;
// then s_barrier; s_waitcnt lgkmcnt(0); sched_barrier(0) (rule 18); MFMAs;
// s_barrier. Staging ring and vmcnt counts identical to R2/R3 (verified).
// Requires M%256==0, N%256==0, K%128==0.
template<int OUTF32>
__global__ __launch_bounds__(512, 2) void gemm256_kernel(
    const u16* __restrict__ A, const u16* __restrict__ B,
    void* __restrict__ Cv, const float* __restrict__ addf,
    const u16* __restrict__ addb, const float* __restrict__ biasN,
    int M, int N, int K)
{
    extern __shared__ u16 lds[];            // 131072 B
    u16* Abase = lds;                       // A slots: (buf*2+half)*16384 B
    u16* Bbase = lds + 32768;               // B slots likewise

    const int tid  = threadIdx.x;
    const int lane = tid & 63;
    const int wave = tid >> 6;              // 0..7
    const int wm   = wave >> 2;             // 0..1
    const int wn   = wave & 3;              // 0..3
    const int row0 = blockIdx.y * 256;
    const int col0 = blockIdx.x * 256;

    // staging lane mapping (verified swizzle)
    const int srow = lane >> 2;
    const int scol = ((lane & 3) ^ ((lane >> 3) & 3)) * 8;

    const u16* pA = A + (size_t)(row0 + wave*16 + srow) * K + scol;
    const u16* pB = B + (size_t)(col0 + wave*16 + srow) * K + scol;
    const size_t h128 = (size_t)128 * K;    // uniform (+128 rows)

    const int ldsW = wave * 1024;           // wave's subtile pair (u16 units)

    // fragment read slot (bytes)
    const int fr = lane & 15;
    const int fq8 = lane >> 4;
    const int fByte = (4*fr + (fq8 ^ ((fr >> 1) & 3))) * 16;

    // raw AS3 base addresses for asm reads
    const u32 uA = ldsaddr(Abase) + (u32)(wm * 16384) + (u32)fByte;
    const u32 uB = ldsaddr(Bbase) + (u32)((wn >> 1) * 16384 + (wn & 1) * 8192) + (u32)fByte;

    frag_cd acc[8][4] = {};
    frag_ab bfr[4][2];
    frag_ab afr[2][2];

#define STAGE256(SRC, DSTOFF, KT)                                   \
    gld16((SRC) + (KT),      (DSTOFF) + ldsW);                      \
    gld16((SRC) + (KT) + 32, (DSTOFF) + ldsW + 512);

    // prologue: B(t0)h0, B(t0)h1, A(t0)h0, A(t0)h1, B(t1)h0, B(t1)h1
    STAGE256(pB,        Bbase + 0*8192, 0);
    STAGE256(pB + h128, Bbase + 1*8192, 0);
    STAGE256(pA,        Abase + 0*8192, 0);
    STAGE256(pA + h128, Abase + 1*8192, 0);
    STAGE256(pB,        Bbase + 2*8192, 64);
    STAGE256(pB + h128, Bbase + 3*8192, 64);
    asm volatile("s_waitcnt vmcnt(4)" ::: "memory");   // tile0 resident
    __builtin_amdgcn_s_barrier();

    const int NI = K >> 7;                  // K/128
    for (int i = 0; i < NI; ++i) {
        const int t1k = i*128 + 64;
        int t2k = i*128 + 128; if (t2k >= K) t2k = K - 64;  // last-iter garbage (unread)
        int t3k = i*128 + 192; if (t3k >= K) t3k = K - 64;

        #pragma unroll
        for (int p = 0; p < 8; ++p) {
            const int q = p & 3;
            const int bufc = p >> 2;

            // ---- phase-top LDS reads (asm; drain staggered under barrier) ----
            if (q == 0) {                   // 8 B-frags for this K-tile
                #pragma unroll
                for (int n = 0; n < 4; ++n)
                    #pragma unroll
                    for (int ks = 0; ks < 2; ++ks)
                        bfr[n][ks] = dsread16(uB + (u32)(bufc*32768 + (n*2 + ks)*1024));
            }
            #pragma unroll
            for (int r = 0; r < 2; ++r)
                #pragma unroll
                for (int ks = 0; ks < 2; ++ks)
                    afr[r][ks] = dsread16(uA + (u32)(bufc*32768 + ((2*q + r)*2 + ks)*1024));

            // ---- stage next half-tile ----
            switch (p) {
                case 0: STAGE256(pA,        Abase + 2*8192, t1k); break;
                case 1: STAGE256(pA + h128, Abase + 3*8192, t1k); break;
                case 2: STAGE256(pB,        Bbase + 0*8192, t2k); break;
                case 3: STAGE256(pB + h128, Bbase + 1*8192, t2k); break;
                case 4: STAGE256(pA,        Abase + 0*8192, t2k); break;
                case 5: STAGE256(pA + h128, Abase + 1*8192, t2k); break;
                case 6: STAGE256(pB,        Bbase + 2*8192, t3k); break;
                case 7: STAGE256(pB + h128, Bbase + 3*8192, t3k); break;
            }
            if (q == 0) asm volatile("s_waitcnt lgkmcnt(8)" ::: "memory"); // 12-read throttle
            if (q == 3) asm volatile("s_waitcnt vmcnt(4)" ::: "memory");   // counted, never 0
            __builtin_amdgcn_s_barrier();
            asm volatile("s_waitcnt lgkmcnt(0)" ::: "memory");
            __builtin_amdgcn_sched_barrier(0);

            __builtin_amdgcn_s_setprio(1);
            #pragma unroll
            for (int ks = 0; ks < 2; ++ks)
                #pragma unroll
                for (int r = 0; r < 2; ++r)
                    #pragma unroll
                    for (int n = 0; n < 4; ++n)
                        acc[2*q + r][n] = __builtin_amdgcn_mfma_f32_16x16x32_bf16(
                            afr[r][ks], bfr[n][ks], acc[2*q + r][n], 0, 0, 0);
            __builtin_amdgcn_s_setprio(0);
            __builtin_amdgcn_s_barrier();
        }
    }
    asm volatile("s_waitcnt vmcnt(0)" ::: "memory");   // drain pending LDS DMA
#undef STAGE256

    #pragma unroll
    for (int m = 0; m < 8; ++m) {
        #pragma unroll
        for (int n = 0; n < 4; ++n) {
            #pragma unroll
            for (int r = 0; r < 4; ++r) {
                const int grow = row0 + wm*128 + m*16 + (lane >> 4) * 4 + r;
                const int gcol = col0 + wn*64 + n*16 + (lane & 15);
                const size_t idx = (size_t)grow * N + gcol;
                float v = acc[m][n][r];
                if (addf) v += addf[idx];
                if (addb) v += bf2f(addb[idx]);
                if (biasN) v += biasN[gcol];
                if (OUTF32) reinterpret_cast<float*>(Cv)[idx] = v;
                else        reinterpret_cast<u16*>(Cv)[idx] = f2bf(v);
            }
        }
    }
}

// ---------- launch ----------
extern "C" void kernel_launch(void* const* d_in, const int* in_sizes, int n_in,
                              void* d_out, int out_size, void* d_ws, size_t ws_size,
                              hipStream_t stream)
{
    const float* x          = (const float*)d_in[0];
    const float* gist_theta = (const float*)d_in[1];
    const float* gist_mag   = (const float*)d_in[2];
    const float* gist_wts   = (const float*)d_in[3];
    const float* ln_sheaf_w = (const float*)d_in[4];
    const float* ln_sheaf_b = (const float*)d_in[5];
    const float* sheaf_th   = (const float*)d_in[6];
    const float* alpha      = (const float*)d_in[7];
    const float* corr_W     = (const float*)d_in[8];
    const float* ln_gist_w  = (const float*)d_in[9];
    const float* ln_gist_b  = (const float*)d_in[10];
    const float* strength   = (const float*)d_in[11];
    const float* gr_w       = (const float*)d_in[12];
    const float* gr_b       = (const float*)d_in[13];
    const float* gca_w      = (const float*)d_in[14];
    const float* gca_b      = (const float*)d_in[15];
    const float* Wq         = (const float*)d_in[16];
    const float* Wk         = (const float*)d_in[17];
    const float* Wv         = (const float*)d_in[18];
    const float* Wo         = (const float*)d_in[19];
    const float* up_W       = (const float*)d_in[20];
    const float* up_b       = (const float*)d_in[21];
    float* out = (float*)d_out;

    static bool attr_done = false;
    if (!attr_done) {
        hipFuncSetAttribute((const void*)&gemm256_kernel<0>,
                            hipFuncAttributeMaxDynamicSharedMemorySize, 131072);
        hipFuncSetAttribute((const void*)&gemm256_kernel<1>,
                            hipFuncAttributeMaxDynamicSharedMemorySize, 131072);
        attr_done = true;
    }

    char* w = (char*)d_ws;
    const size_t BIG = (size_t)4 * 2048 * 2048 * sizeof(u16);  // 33.5 MB
    u16* wA = (u16*)(w);                 // x1 -> xA -> x2(in-place) -> ctx
    u16* wB = (u16*)(w + BIG);           // WkWv(16.8MB) -> pre -> Q
    u16* wC = (u16*)(w + 2*BIG);         // Abuf(pad) -> xB
    u16* wslot = (u16*)(w + 3*BIG);      // Bbuf(pad) / single bf16 weight (8.4 MB)
    char* small = w + 3*BIG + (size_t)2048*2048*sizeof(u16);
    float* sheaf_cs = (float*)(small);
    float* gist_cs  = (float*)(small + 32768);
    u16* repr = (u16*)(small + 65536);            // 64x2048 bf16 (256 KB)
    u16* KV   = repr + 64*2048;                   // 64x4096 bf16 (512 KB)
    float* part = (float*)((char*)KV + (size_t)64*4096*sizeof(u16));  // K-split partials
    const size_t part_bytes = (size_t)8 * 64 * 4096 * sizeof(float);  // 8 MB max
    const bool ksplit = ws_size >= (size_t)((char*)part - w) + part_bytes;

    const int W4 = 2048*2048/4;   // float4 groups per weight matrix
    const dim3 gBig256(2048/256, 8192/256), gKV(32, 1), gRepr(16, 1);

    setup_kernel<<<8, 256, 0, stream>>>(sheaf_th, gist_theta, gist_mag, gist_wts,
                                        strength, sheaf_cs, gist_cs);

    // gist_repr = concat(theta,mag) @ up_W^T + up_b   (K padded to 1056)
    apad_kernel<<<64, 256, 0, stream>>>(gist_theta, gist_mag, wC);
    wpad_kernel<<<2048, 256, 0, stream>>>(up_W, wslot);
    if (ksplit) {
        gemm_bt_kernel<2><<<dim3(16,1,4), 256, 0, stream>>>(wC, wslot, part,
                                                 nullptr, nullptr, nullptr, 64, 2048, 1056);
        ksum_kernel<<<(64*2048/4 + 255)/256, 256, 0, stream>>>(part, 4, 64*2048/4, 2048,
                                                 up_b, repr);
    } else {
        gemm_bt_kernel<0><<<gRepr, 256, 0, stream>>>(wC, wslot, repr, nullptr, nullptr, up_b,
                                                     64, 2048, 1056);
    }

    // KV = repr @ [Wk;Wv]^T  (one N=4096 GEMM; WkWv staged bf16 in wB)
    convert_kernel<<<4096, 256, 0, stream>>>(Wk, wB, W4);
    convert_kernel<<<4096, 256, 0, stream>>>(Wv, wB + (size_t)2048*2048, W4);
    if (ksplit) {
        gemm_bt_kernel<2><<<dim3(32,1,8), 256, 0, stream>>>(repr, wB, part,
                                                 nullptr, nullptr, nullptr, 64, 4096, 2048);
        ksum_kernel<<<(64*4096/4 + 255)/256, 256, 0, stream>>>(part, 8, 64*4096/4, 4096,
                                                 nullptr, KV);
    } else {
        gemm_bt_kernel<0><<<gKV, 256, 0, stream>>>(repr, wB, KV, nullptr, nullptr, nullptr,
                                                   64, 4096, 2048);
    }

    ln_kernel<<<8192, 256, 0, stream>>>(x, ln_sheaf_w, ln_sheaf_b, wA);        // x1
    sheaf_kernel<<<8192, 256, 0, stream>>>(wA, sheaf_cs, alpha, wB);           // pre

    convert_kernel<<<4096, 256, 0, stream>>>(corr_W, wslot, W4);
    gemm256_kernel<0><<<gBig256, 512, 131072, stream>>>(wB, wslot, wA, x, wB, nullptr,
                                                8192, 2048, 2048);             // xA = x + pre + pre@corr^T
    stage2_kernel<<<8192, 256, 0, stream>>>(wA, gist_cs, ln_gist_w, ln_gist_b,
                                            gr_w, gr_b, gca_w, gca_b,
                                            wC, wA);                           // xB, x2
    convert_kernel<<<4096, 256, 0, stream>>>(Wq, wslot, W4);
    gemm256_kernel<0><<<gBig256, 512, 131072, stream>>>(wA, wslot, wB, nullptr, nullptr, nullptr,
                                                8192, 2048, 2048);             // Q
    attn_kernel<<<2048, 256, 0, stream>>>(wB, KV, wA);                         // ctx
    convert_kernel<<<4096, 256, 0, stream>>>(Wo, wslot, W4);
    gemm256_kernel<1><<<gBig256, 512, 131072, stream>>>(wA, wslot, (void*)out, nullptr, wC, nullptr,
                                                8192, 2048, 2048);             // out = xB + ctx@Wo^T
}

// Round 5
// 633.171 us; speedup vs baseline: 1.3745x; 1.0221x over previous
//
#include <hip/hip_runtime.h>
#include <hip/hip_bf16.h>

typedef unsigned short u16;
typedef unsigned int   u32;

using frag_ab = __attribute__((ext_vector_type(8))) short;  // 8 bf16
using frag_cd = __attribute__((ext_vector_type(4))) float;  // 4 fp32

// ---------- bf16 helpers ----------
__device__ __forceinline__ float bf2f(u16 u) {
    union { u32 i; float f; } v; v.i = ((u32)u) << 16; return v.f;
}
__device__ __forceinline__ u16 f2bf(float f) {
    __hip_bfloat16 h = __float2bfloat16(f);
    u16 u; __builtin_memcpy(&u, &h, 2); return u;
}
__device__ __forceinline__ float lo2f(u32 u) { union { u32 i; float f; } v; v.i = u << 16; return v.f; }
__device__ __forceinline__ float hi2f(u32 u) { union { u32 i; float f; } v; v.i = u & 0xffff0000u; return v.f; }
__device__ __forceinline__ void unpack8(uint4 v, float* f) {
    f[0]=lo2f(v.x); f[1]=hi2f(v.x); f[2]=lo2f(v.y); f[3]=hi2f(v.y);
    f[4]=lo2f(v.z); f[5]=hi2f(v.z); f[6]=lo2f(v.w); f[7]=hi2f(v.w);
}
__device__ __forceinline__ void load4f(const u16* p, float* f) {
    ushort4 v = *reinterpret_cast<const ushort4*>(p);
    f[0]=bf2f(v.x); f[1]=bf2f(v.y); f[2]=bf2f(v.z); f[3]=bf2f(v.w);
}
__device__ __forceinline__ void store4bf(u16* p, const float* f) {
    ushort4 v; v.x=f2bf(f[0]); v.y=f2bf(f[1]); v.z=f2bf(f[2]); v.w=f2bf(f[3]);
    *reinterpret_cast<ushort4*>(p) = v;
}
__device__ __forceinline__ u32 pack2(float a, float b) {
    return (u32)f2bf(a) | ((u32)f2bf(b) << 16);
}

// async global->LDS DMA, 16B per lane; lds dest = wave-uniform base + lane*16
__device__ __forceinline__ void gld16(const u16* g, u16* l) {
    __builtin_amdgcn_global_load_lds(
        (const __attribute__((address_space(1))) u32*)g,
        (__attribute__((address_space(3))) u32*)l, 16, 0, 0);
}

// raw LDS byte address (address-space 3 offset) of a __shared__ pointer
__device__ __forceinline__ u32 ldsaddr(const u16* p) {
    return (u32)(uintptr_t)(const __attribute__((address_space(3))) u16*)p;
}

// inline-asm ds_read_b128 (hazards handled by our explicit barrier protocol)
__device__ __forceinline__ frag_ab dsread16(u32 a) {
    frag_ab r;
    asm volatile("ds_read_b128 %0, %1" : "=v"(r) : "v"(a));
    return r;
}

// ---------- block reduction (256 threads = 4 waves) ----------
__device__ __forceinline__ void block_reduce2(float& s, float& ss, float* red) {
    #pragma unroll
    for (int off = 32; off > 0; off >>= 1) {
        s  += __shfl_down(s, off, 64);
        ss += __shfl_down(ss, off, 64);
    }
    int wv = threadIdx.x >> 6, ln = threadIdx.x & 63;
    if (ln == 0) { red[wv*2] = s; red[wv*2+1] = ss; }
    __syncthreads();
    s  = red[0] + red[2] + red[4] + red[6];
    ss = red[1] + red[3] + red[5] + red[7];
    __syncthreads();
}

// ---------- fp32 -> bf16 conversion (n4 = n/4 float4 groups) ----------
__global__ __launch_bounds__(256) void convert_kernel(
    const float* __restrict__ in, u16* __restrict__ out, int n4)
{
    int i = blockIdx.x * 256 + threadIdx.x;
    if (i < n4) {
        float4 v = reinterpret_cast<const float4*>(in)[i];
        ushort4 o; o.x=f2bf(v.x); o.y=f2bf(v.y); o.z=f2bf(v.z); o.w=f2bf(v.w);
        reinterpret_cast<ushort4*>(out)[i] = o;
    }
}

// batched converts: blockIdx.y selects (src,dst) pair
__global__ __launch_bounds__(256) void convert2_kernel(
    const float* __restrict__ s0, const float* __restrict__ s1,
    u16* __restrict__ d0, u16* __restrict__ d1, int n4)
{
    int i = blockIdx.x * 256 + threadIdx.x;
    if (i >= n4) return;
    const float* s = blockIdx.y ? s1 : s0;
    u16*         d = blockIdx.y ? d1 : d0;
    float4 v = reinterpret_cast<const float4*>(s)[i];
    ushort4 o; o.x=f2bf(v.x); o.y=f2bf(v.y); o.z=f2bf(v.z); o.w=f2bf(v.w);
    reinterpret_cast<ushort4*>(d)[i] = o;
}

__global__ __launch_bounds__(256) void convert3_kernel(
    const float* __restrict__ s0, const float* __restrict__ s1,
    const float* __restrict__ s2,
    u16* __restrict__ d0, u16* __restrict__ d1, u16* __restrict__ d2, int n4)
{
    int i = blockIdx.x * 256 + threadIdx.x;
    if (i >= n4) return;
    const float* s = blockIdx.y == 0 ? s0 : (blockIdx.y == 1 ? s1 : s2);
    u16*         d = blockIdx.y == 0 ? d0 : (blockIdx.y == 1 ? d1 : d2);
    float4 v = reinterpret_cast<const float4*>(s)[i];
    ushort4 o; o.x=f2bf(v.x); o.y=f2bf(v.y); o.z=f2bf(v.z); o.w=f2bf(v.w);
    reinterpret_cast<ushort4*>(d)[i] = o;
}

// ---------- pad concat(theta,mag) -> Abuf (64 x 1056 bf16) ----------
__global__ __launch_bounds__(256) void apad_kernel(
    const float* __restrict__ gth, const float* __restrict__ gmag,
    u16* __restrict__ Abuf)
{
    const int r = blockIdx.x;             // 0..63
    const int tid = threadIdx.x;
    for (int c0 = tid*4; c0 < 1056; c0 += 1024) {
        float f[4];
        #pragma unroll
        for (int i = 0; i < 4; ++i) {
            int c = c0 + i;
            f[i] = (c < 1024) ? gth[(size_t)r*1024 + c] : (c == 1024 ? gmag[r] : 0.f);
        }
        store4bf(Abuf + (size_t)r*1056 + c0, f);
    }
}

// ---------- pad up_W (2048 x 1025 fp32) -> Bbuf (2048 x 1056 bf16) ----------
__global__ __launch_bounds__(256) void wpad_kernel(
    const float* __restrict__ upW, u16* __restrict__ Bbuf)
{
    const int r = blockIdx.x;             // 0..2047
    const int tid = threadIdx.x;
    for (int c0 = tid*4; c0 < 1056; c0 += 1024) {
        float f[4];
        #pragma unroll
        for (int i = 0; i < 4; ++i) {
            int c = c0 + i;
            f[i] = (c < 1025) ? upW[(size_t)r*1025 + c] : 0.f;
        }
        store4bf(Bbuf + (size_t)r*1056 + c0, f);
    }
}

// ---------- setup: cos/sin tables ----------
__global__ __launch_bounds__(256) void setup_kernel(
    const float* __restrict__ sheaf_th, const float* __restrict__ gth,
    const float* __restrict__ gmag, const float* __restrict__ gwts,
    const float* __restrict__ strength, float* __restrict__ sheaf_cs,
    float* __restrict__ gist_cs)
{
    int bx = blockIdx.x, tid = threadIdx.x;
    if (bx < 4) {
        for (int j = tid; j < 1024; j += 256) {
            float th = sheaf_th[bx*1024 + j];
            sheaf_cs[bx*1024 + j]        = cosf(th);
            sheaf_cs[4096 + bx*1024 + j] = sinf(th);
        }
    } else {
        int b = bx - 4;
        float w[16], wsum = 0.f;
        #pragma unroll
        for (int k = 0; k < 16; ++k) {
            w[k] = gwts[b*16+k] * gmag[b*16+k];
            wsum += w[k];
        }
        float inv = 1.f / (wsum + 1e-8f);
        float sig = 1.f / (1.f + expf(-strength[0]));
        for (int j = tid; j < 1024; j += 256) {
            float th = 0.f;
            #pragma unroll
            for (int k = 0; k < 16; ++k)
                th += w[k] * inv * gth[(size_t)(b*16+k)*1024 + j];
            th *= sig;
            gist_cs[b*1024 + j]        = cosf(th);
            gist_cs[4096 + b*1024 + j] = sinf(th);
        }
    }
}

// ---------- LN over rows of 2048: fp32 in -> bf16 out ----------
__global__ __launch_bounds__(256) void ln_kernel(
    const float* __restrict__ in, const float* __restrict__ w,
    const float* __restrict__ b, u16* __restrict__ out)
{
    __shared__ float red[8];
    const size_t base = (size_t)blockIdx.x * 2048;
    const int e0 = threadIdx.x * 8;
    float x[8];
    *reinterpret_cast<float4*>(&x[0]) = *reinterpret_cast<const float4*>(in + base + e0);
    *reinterpret_cast<float4*>(&x[4]) = *reinterpret_cast<const float4*>(in + base + e0 + 4);
    float s = 0.f, ss = 0.f;
    #pragma unroll
    for (int i = 0; i < 8; ++i) { s += x[i]; ss += x[i]*x[i]; }
    block_reduce2(s, ss, red);
    const float mu = s * (1.f/2048.f);
    const float rin = rsqrtf(ss * (1.f/2048.f) - mu*mu + 1e-5f);
    float wv[8], bv[8];
    *reinterpret_cast<float4*>(&wv[0]) = *reinterpret_cast<const float4*>(w + e0);
    *reinterpret_cast<float4*>(&wv[4]) = *reinterpret_cast<const float4*>(w + e0 + 4);
    *reinterpret_cast<float4*>(&bv[0]) = *reinterpret_cast<const float4*>(b + e0);
    *reinterpret_cast<float4*>(&bv[4]) = *reinterpret_cast<const float4*>(b + e0 + 4);
    float o[8];
    #pragma unroll
    for (int i = 0; i < 8; ++i) o[i] = (x[i]-mu)*rin*wv[i] + bv[i];
    uint4 st = { pack2(o[0],o[1]), pack2(o[2],o[3]), pack2(o[4],o[5]), pack2(o[6],o[7]) };
    *reinterpret_cast<uint4*>(out + base + e0) = st;
}

// ---------- sheaf: pre = x1 - |alpha| * (4*x1 - sum rot_inv(shift(x1))) ----------
__global__ __launch_bounds__(256) void sheaf_kernel(
    const u16* __restrict__ x1, const float* __restrict__ scs,
    const float* __restrict__ alpha_p, u16* __restrict__ pre)
{
    const int row = blockIdx.x;
    const int t = row & 2047;
    const int j0 = threadIdx.x * 4;
    const size_t base = (size_t)row * 2048;
    const float a = fabsf(alpha_p[0]);

    float xr[4], xi[4];
    load4f(x1 + base + j0, xr);
    load4f(x1 + base + 1024 + j0, xi);
    float lr[4], li[4];
    #pragma unroll
    for (int m = 0; m < 4; ++m) { lr[m] = 4.f*xr[m]; li[m] = 4.f*xi[m]; }

    #pragma unroll
    for (int idx = 0; idx < 4; ++idx) {
        const int sh = 3 - idx;
        if (t >= sh) {
            const float4 c4 = *reinterpret_cast<const float4*>(&scs[idx*1024 + j0]);
            const float4 s4 = *reinterpret_cast<const float4*>(&scs[4096 + idx*1024 + j0]);
            float c[4] = {c4.x, c4.y, c4.z, c4.w};
            float sn[4] = {s4.x, s4.y, s4.z, s4.w};
            float yr[4], yi[4];
            load4f(x1 + base - (size_t)sh*2048 + j0, yr);
            load4f(x1 + base - (size_t)sh*2048 + 1024 + j0, yi);
            #pragma unroll
            for (int m = 0; m < 4; ++m) {
                lr[m] -= yr[m]*c[m] + yi[m]*sn[m];     // rot_inv real
                li[m] -= yi[m]*c[m] - yr[m]*sn[m];     // rot_inv imag
            }
        }
    }
    float pr[4], pi[4];
    #pragma unroll
    for (int m = 0; m < 4; ++m) { pr[m] = xr[m] - a*lr[m]; pi[m] = xi[m] - a*li[m]; }
    store4bf(pre + base + j0, pr);
    store4bf(pre + base + 1024 + j0, pi);
}

// ---------- stage2: xn=LN(xA); g=LN(rot(xn)); xB=xA-xn+g; x2=LN(xB) ----------
__global__ __launch_bounds__(256) void stage2_kernel(
    const u16* __restrict__ xA, const float* __restrict__ gcs,
    const float* __restrict__ lgw, const float* __restrict__ lgb,
    const float* __restrict__ grw, const float* __restrict__ grb,
    const float* __restrict__ gcaw, const float* __restrict__ gcab,
    u16* __restrict__ xB, u16* __restrict__ x2)
{
    __shared__ float red[8];
    const int row = blockIdx.x;
    const int b = row >> 11;
    const int j0 = threadIdx.x * 4;
    const size_t base = (size_t)row * 2048;

    float ar[4], ai[4];
    load4f(xA + base + j0, ar);
    load4f(xA + base + 1024 + j0, ai);

    float s = 0.f, ss = 0.f;
    #pragma unroll
    for (int m = 0; m < 4; ++m) { s += ar[m]+ai[m]; ss += ar[m]*ar[m] + ai[m]*ai[m]; }
    block_reduce2(s, ss, red);
    float mu = s * (1.f/2048.f);
    float rin = rsqrtf(ss * (1.f/2048.f) - mu*mu + 1e-5f);

    float w0[4], b0[4], w1[4], b1[4];
    *reinterpret_cast<float4*>(w0) = *reinterpret_cast<const float4*>(lgw + j0);
    *reinterpret_cast<float4*>(b0) = *reinterpret_cast<const float4*>(lgb + j0);
    *reinterpret_cast<float4*>(w1) = *reinterpret_cast<const float4*>(lgw + 1024 + j0);
    *reinterpret_cast<float4*>(b1) = *reinterpret_cast<const float4*>(lgb + 1024 + j0);
    float xnr[4], xni[4];
    #pragma unroll
    for (int m = 0; m < 4; ++m) {
        xnr[m] = (ar[m]-mu)*rin*w0[m] + b0[m];
        xni[m] = (ai[m]-mu)*rin*w1[m] + b1[m];
    }

    const float4 c4 = *reinterpret_cast<const float4*>(&gcs[b*1024 + j0]);
    const float4 s4 = *reinterpret_cast<const float4*>(&gcs[4096 + b*1024 + j0]);
    float c[4] = {c4.x, c4.y, c4.z, c4.w};
    float sn[4] = {s4.x, s4.y, s4.z, s4.w};
    float rr[4], ri[4];
    #pragma unroll
    for (int m = 0; m < 4; ++m) {
        rr[m] = xnr[m]*c[m] - xni[m]*sn[m];
        ri[m] = xnr[m]*sn[m] + xni[m]*c[m];
    }

    s = 0.f; ss = 0.f;
    #pragma unroll
    for (int m = 0; m < 4; ++m) { s += rr[m]+ri[m]; ss += rr[m]*rr[m] + ri[m]*ri[m]; }
    block_reduce2(s, ss, red);
    float mu2 = s * (1.f/2048.f);
    float rin2 = rsqrtf(ss * (1.f/2048.f) - mu2*mu2 + 1e-5f);

    *reinterpret_cast<float4*>(w0) = *reinterpret_cast<const float4*>(grw + j0);
    *reinterpret_cast<float4*>(b0) = *reinterpret_cast<const float4*>(grb + j0);
    *reinterpret_cast<float4*>(w1) = *reinterpret_cast<const float4*>(grw + 1024 + j0);
    *reinterpret_cast<float4*>(b1) = *reinterpret_cast<const float4*>(grb + 1024 + j0);
    float br[4], bi[4];
    #pragma unroll
    for (int m = 0; m < 4; ++m) {
        float gr_ = (rr[m]-mu2)*rin2*w0[m] + b0[m];
        float gi_ = (ri[m]-mu2)*rin2*w1[m] + b1[m];
        br[m] = ar[m] - xnr[m] + gr_;
        bi[m] = ai[m] - xni[m] + gi_;
    }
    store4bf(xB + base + j0, br);
    store4bf(xB + base + 1024 + j0, bi);

    s = 0.f; ss = 0.f;
    #pragma unroll
    for (int m = 0; m < 4; ++m) { s += br[m]+bi[m]; ss += br[m]*br[m] + bi[m]*bi[m]; }
    block_reduce2(s, ss, red);
    float mu3 = s * (1.f/2048.f);
    float rin3 = rsqrtf(ss * (1.f/2048.f) - mu3*mu3 + 1e-5f);

    *reinterpret_cast<float4*>(w0) = *reinterpret_cast<const float4*>(gcaw + j0);
    *reinterpret_cast<float4*>(b0) = *reinterpret_cast<const float4*>(gcab + j0);
    *reinterpret_cast<float4*>(w1) = *reinterpret_cast<const float4*>(gcaw + 1024 + j0);
    *reinterpret_cast<float4*>(b1) = *reinterpret_cast<const float4*>(gcab + 1024 + j0);
    float o0[4], o1[4];
    #pragma unroll
    for (int m = 0; m < 4; ++m) {
        o0[m] = (br[m]-mu3)*rin3*w0[m] + b0[m];
        o1[m] = (bi[m]-mu3)*rin3*w1[m] + b1[m];
    }
    store4bf(x2 + base + j0, o0);
    store4bf(x2 + base + 1024 + j0, o1);
}

// ---------- cross-attention over K=16 gist tokens: wave per (b,t) ----------
// KV combined: row (b*16+k) has Kh at [0,2048), V at [2048,4096)
__global__ __launch_bounds__(256) void attn_kernel(
    const u16* __restrict__ Q, const u16* __restrict__ KV,
    u16* __restrict__ ctx)
{
    const int wv = threadIdx.x >> 6;
    const int lane = threadIdx.x & 63;
    const int tg = blockIdx.x * 4 + wv;     // 0..8191
    const int b = tg >> 11;
    const size_t base = (size_t)tg * 2048 + lane * 32;

    float q[32];
    #pragma unroll
    for (int c = 0; c < 4; ++c)
        unpack8(*reinterpret_cast<const uint4*>(Q + base + c*8), &q[c*8]);

    float sc[16];
    #pragma unroll
    for (int k = 0; k < 16; ++k) {
        const u16* kr = KV + (size_t)(b*16 + k) * 4096 + lane*32;
        float p = 0.f;
        #pragma unroll
        for (int c = 0; c < 4; ++c) {
            float kv8[8]; unpack8(*reinterpret_cast<const uint4*>(kr + c*8), kv8);
            #pragma unroll
            for (int e = 0; e < 8; ++e) p += q[c*8+e] * kv8[e];
        }
        sc[k] = p;
    }
    #pragma unroll
    for (int k = 0; k < 16; ++k) {
        sc[k] += __shfl_xor(sc[k], 1, 64);
        sc[k] += __shfl_xor(sc[k], 2, 64);
        sc[k] *= 0.08838834764831845f;   // 1/sqrt(128)
    }
    float m = sc[0];
    #pragma unroll
    for (int k = 1; k < 16; ++k) m = fmaxf(m, sc[k]);
    float sum = 0.f;
    #pragma unroll
    for (int k = 0; k < 16; ++k) { sc[k] = expf(sc[k]-m); sum += sc[k]; }
    const float inv = 1.f / sum;

    float o[32];
    #pragma unroll
    for (int e = 0; e < 32; ++e) o[e] = 0.f;
    #pragma unroll
    for (int k = 0; k < 16; ++k) {
        const float p = sc[k] * inv;
        const u16* vr = KV + (size_t)(b*16 + k) * 4096 + 2048 + lane*32;
        #pragma unroll
        for (int c = 0; c < 4; ++c) {
            float v8[8]; unpack8(*reinterpret_cast<const uint4*>(vr + c*8), v8);
            #pragma unroll
            for (int e = 0; e < 8; ++e) o[c*8+e] += p * v8[e];
        }
    }
    #pragma unroll
    for (int c = 0; c < 4; ++c) {
        uint4 st = { pack2(o[c*8+0],o[c*8+1]), pack2(o[c*8+2],o[c*8+3]),
                     pack2(o[c*8+4],o[c*8+5]), pack2(o[c*8+6],o[c*8+7]) };
        *reinterpret_cast<uint4*>(ctx + base + c*8) = st;
    }
}

// ---------- small-shape MFMA GEMM (128x128 tile, 2-phase dbuf) ----------
// OUTMODE: 0 = bf16 out (+adds), 1 = f32 out (+adds),
//          2 = f32 partial per blockIdx.z K-chunk (no adds) for K-split
#define BM 128
#define BN 128
#define BK 32

template<int OUTMODE>
__global__ __launch_bounds__(256, 4) void gemm_bt_kernel(
    const u16* __restrict__ A, const u16* __restrict__ B,
    void* __restrict__ Cv, const float* __restrict__ addf,
    const u16* __restrict__ addb, const float* __restrict__ biasN,
    int M, int N, int K)
{
    __shared__ u16 As[2][8*512];
    __shared__ u16 Bs[2][8*512];

    const int tid = threadIdx.x;
    const int lane = tid & 63;
    const int wave = tid >> 6;       // 0..3
    const int wm = wave >> 1;        // 0..1
    const int wn = wave & 1;         // 0..1
    const int row0 = blockIdx.y * BM;
    const int col0 = blockIdx.x * BN;

    frag_cd acc[4][4] = {};

    const int srow   = lane >> 2;
    const int schunk = (lane & 3) ^ ((lane >> 3) & 3);
    const int scol   = schunk * 8;
    const int s0 = wave, s1 = wave + 4;

    int ra0 = row0 + s0*16 + srow; if (ra0 >= M) ra0 = M - 1;
    int ra1 = row0 + s1*16 + srow; if (ra1 >= M) ra1 = M - 1;
    const u16* gA0 = A + (size_t)ra0 * K + scol;
    const u16* gA1 = A + (size_t)ra1 * K + scol;
    const u16* gB0 = B + (size_t)(col0 + s0*16 + srow) * K + scol;
    const u16* gB1 = B + (size_t)(col0 + s1*16 + srow) * K + scol;

    const int fr = lane & 15;
    const int fq8 = lane >> 4;
    const int fslot = (4*fr + (fq8 ^ ((fr >> 1) & 3))) * 8;

    const int nsteps = K / BK;
    int ts = 0, te = nsteps;
    if (OUTMODE == 2) {
        ts = (nsteps * (int)blockIdx.z) / (int)gridDim.z;
        te = (nsteps * ((int)blockIdx.z + 1)) / (int)gridDim.z;
    }

    gld16(gA0 + ts*BK, &As[0][s0*512]);
    gld16(gA1 + ts*BK, &As[0][s1*512]);
    gld16(gB0 + ts*BK, &Bs[0][s0*512]);
    gld16(gB1 + ts*BK, &Bs[0][s1*512]);
    __syncthreads();

    int cur = 0;
    for (int t = ts; t < te; ++t) {
        if (t + 1 < te) {
            const int kt = (t + 1) * BK;
            gld16(gA0 + kt, &As[cur^1][s0*512]);
            gld16(gA1 + kt, &As[cur^1][s1*512]);
            gld16(gB0 + kt, &Bs[cur^1][s0*512]);
            gld16(gB1 + kt, &Bs[cur^1][s1*512]);
        }

        frag_ab af[4], bf_[4];
        #pragma unroll
        for (int i = 0; i < 4; ++i)
            af[i] = *reinterpret_cast<const frag_ab*>(&As[cur][(wm*4 + i)*512 + fslot]);
        #pragma unroll
        for (int j = 0; j < 4; ++j)
            bf_[j] = *reinterpret_cast<const frag_ab*>(&Bs[cur][(wn*4 + j)*512 + fslot]);
        #pragma unroll
        for (int i = 0; i < 4; ++i)
            #pragma unroll
            for (int j = 0; j < 4; ++j)
                acc[i][j] = __builtin_amdgcn_mfma_f32_16x16x32_bf16(af[i], bf_[j], acc[i][j], 0, 0, 0);

        __syncthreads();
        cur ^= 1;
    }

    float* Pz = (OUTMODE == 2)
        ? reinterpret_cast<float*>(Cv) + (size_t)blockIdx.z * M * N : nullptr;

    #pragma unroll
    for (int i = 0; i < 4; ++i) {
        #pragma unroll
        for (int j = 0; j < 4; ++j) {
            #pragma unroll
            for (int r = 0; r < 4; ++r) {
                const int grow = row0 + wm*64 + i*16 + (lane >> 4) * 4 + r;
                const int gcol = col0 + wn*64 + j*16 + (lane & 15);
                if (grow < M) {
                    const size_t idx = (size_t)grow * N + gcol;
                    float v = acc[i][j][r];
                    if (OUTMODE == 2) {
                        Pz[idx] = v;
                    } else {
                        if (addf) v += addf[idx];
                        if (addb) v += bf2f(addb[idx]);
                        if (biasN) v += biasN[gcol];
                        if (OUTMODE == 1) reinterpret_cast<float*>(Cv)[idx] = v;
                        else              reinterpret_cast<u16*>(Cv)[idx] = f2bf(v);
                    }
                }
            }
        }
    }
}

// ---------- K-split reduce: sum nz fp32 partials (+optional biasN) -> bf16 ----------
__global__ __launch_bounds__(256) void ksum_kernel(
    const float* __restrict__ part, int nz, int n4, int N,
    const float* __restrict__ biasN, u16* __restrict__ out)
{
    int i = blockIdx.x * 256 + threadIdx.x;
    if (i >= n4) return;
    const float4* p4 = reinterpret_cast<const float4*>(part);
    float4 s = p4[i];
    for (int z = 1; z < nz; ++z) {
        float4 t = p4[i + (size_t)z * n4];
        s.x += t.x; s.y += t.y; s.z += t.z; s.w += t.w;
    }
    if (biasN) {
        int col = (i * 4) % N;
        s.x += biasN[col]; s.y += biasN[col+1]; s.z += biasN[col+2]; s.w += biasN[col+3];
    }
    ushort4 o; o.x=f2bf(s.x); o.y=f2bf(s.y); o.z=f2bf(s.z); o.w=f2bf(s.w);
    reinterpret_cast<ushort4*>(out)[i] = o;
}

// ---------- big MFMA GEMM: 256x256 tile, BK=64, 8-phase counted-vmcnt ----------
// v5: + bijective XCD-aware block swizzle (T1). Each XCD now owns a
// contiguous 4-row x 8-col strip of output tiles: 4 A-panels (4 MB = L2)
// reused 8x, B-panels L3-hot. Attacks the measured 4.4x over-fetch
// (FETCH 184 MB vs ~42 ideal on the Q GEMM).
// Schedule unchanged from R4 (asm ds_reads, counted vmcnt(4), setprio).
// Requires M%256==0, N%256==0, K%128==0, grid%8==0 for swizzle.
template<int OUTF32>
__global__ __launch_bounds__(512, 2) void gemm256_kernel(
    const u16* __restrict__ A, const u16* __restrict__ B,
    void* __restrict__ Cv, const float* __restrict__ addf,
    const u16* __restrict__ addb, const float* __restrict__ biasN,
    int M, int N, int K)
{
    extern __shared__ u16 lds[];            // 131072 B
    u16* Abase = lds;                       // A slots: (buf*2+half)*16384 B
    u16* Bbase = lds + 32768;               // B slots likewise

    const int tid  = threadIdx.x;
    const int lane = tid & 63;
    const int wave = tid >> 6;              // 0..7
    const int wm   = wave >> 2;             // 0..1
    const int wn   = wave & 3;              // 0..3

    // bijective XCD swizzle: blocks resident on XCD j work on a contiguous
    // tile strip (nwg % 8 == 0 guaranteed by launch config)
    int id = (int)(blockIdx.y * gridDim.x + blockIdx.x);
    {
        const int nwg = (int)(gridDim.x * gridDim.y);
        if ((nwg & 7) == 0) id = (id & 7) * (nwg >> 3) + (id >> 3);
    }
    const int bx = id % (int)gridDim.x;
    const int by = id / (int)gridDim.x;
    const int row0 = by * 256;
    const int col0 = bx * 256;

    // staging lane mapping (verified swizzle)
    const int srow = lane >> 2;
    const int scol = ((lane & 3) ^ ((lane >> 3) & 3)) * 8;

    const u16* pA = A + (size_t)(row0 + wave*16 + srow) * K + scol;
    const u16* pB = B + (size_t)(col0 + wave*16 + srow) * K + scol;
    const size_t h128 = (size_t)128 * K;    // uniform (+128 rows)

    const int ldsW = wave * 1024;           // wave's subtile pair (u16 units)

    // fragment read slot (bytes)
    const int fr = lane & 15;
    const int fq8 = lane >> 4;
    const int fByte = (4*fr + (fq8 ^ ((fr >> 1) & 3))) * 16;

    // raw AS3 base addresses for asm reads
    const u32 uA = ldsaddr(Abase) + (u32)(wm * 16384) + (u32)fByte;
    const u32 uB = ldsaddr(Bbase) + (u32)((wn >> 1) * 16384 + (wn & 1) * 8192) + (u32)fByte;

    frag_cd acc[8][4] = {};
    frag_ab bfr[4][2];
    frag_ab afr[2][2];

#define STAGE256(SRC, DSTOFF, KT)                                   \
    gld16((SRC) + (KT),      (DSTOFF) + ldsW);                      \
    gld16((SRC) + (KT) + 32, (DSTOFF) + ldsW + 512);

    // prologue: B(t0)h0, B(t0)h1, A(t0)h0, A(t0)h1, B(t1)h0, B(t1)h1
    STAGE256(pB,        Bbase + 0*8192, 0);
    STAGE256(pB + h128, Bbase + 1*8192, 0);
    STAGE256(pA,        Abase + 0*8192, 0);
    STAGE256(pA + h128, Abase + 1*8192, 0);
    STAGE256(pB,        Bbase + 2*8192, 64);
    STAGE256(pB + h128, Bbase + 3*8192, 64);
    asm volatile("s_waitcnt vmcnt(4)" ::: "memory");   // tile0 resident
    __builtin_amdgcn_s_barrier();

    const int NI = K >> 7;                  // K/128
    for (int i = 0; i < NI; ++i) {
        const int t1k = i*128 + 64;
        int t2k = i*128 + 128; if (t2k >= K) t2k = K - 64;  // last-iter garbage (unread)
        int t3k = i*128 + 192; if (t3k >= K) t3k = K - 64;

        #pragma unroll
        for (int p = 0; p < 8; ++p) {
            const int q = p & 3;
            const int bufc = p >> 2;

            // ---- phase-top LDS reads (asm; drain staggered under barrier) ----
            if (q == 0) {                   // 8 B-frags for this K-tile
                #pragma unroll
                for (int n = 0; n < 4; ++n)
                    #pragma unroll
                    for (int ks = 0; ks < 2; ++ks)
                        bfr[n][ks] = dsread16(uB + (u32)(bufc*32768 + (n*2 + ks)*1024));
            }
            #pragma unroll
            for (int r = 0; r < 2; ++r)
                #pragma unroll
                for (int ks = 0; ks < 2; ++ks)
                    afr[r][ks] = dsread16(uA + (u32)(bufc*32768 + ((2*q + r)*2 + ks)*1024));

            // ---- stage next half-tile ----
            switch (p) {
                case 0: STAGE256(pA,        Abase + 2*8192, t1k); break;
                case 1: STAGE256(pA + h128, Abase + 3*8192, t1k); break;
                case 2: STAGE256(pB,        Bbase + 0*8192, t2k); break;
                case 3: STAGE256(pB + h128, Bbase + 1*8192, t2k); break;
                case 4: STAGE256(pA,        Abase + 0*8192, t2k); break;
                case 5: STAGE256(pA + h128, Abase + 1*8192, t2k); break;
                case 6: STAGE256(pB,        Bbase + 2*8192, t3k); break;
                case 7: STAGE256(pB + h128, Bbase + 3*8192, t3k); break;
            }
            if (q == 0) asm volatile("s_waitcnt lgkmcnt(8)" ::: "memory"); // 12-read throttle
            if (q == 3) asm volatile("s_waitcnt vmcnt(4)" ::: "memory");   // counted, never 0
            __builtin_amdgcn_s_barrier();
            asm volatile("s_waitcnt lgkmcnt(0)" ::: "memory");
            __builtin_amdgcn_sched_barrier(0);

            __builtin_amdgcn_s_setprio(1);
            #pragma unroll
            for (int ks = 0; ks < 2; ++ks)
                #pragma unroll
                for (int r = 0; r < 2; ++r)
                    #pragma unroll
                    for (int n = 0; n < 4; ++n)
                        acc[2*q + r][n] = __builtin_amdgcn_mfma_f32_16x16x32_bf16(
                            afr[r][ks], bfr[n][ks], acc[2*q + r][n], 0, 0, 0);
            __builtin_amdgcn_s_setprio(0);
            __builtin_amdgcn_s_barrier();
        }
    }
    asm volatile("s_waitcnt vmcnt(0)" ::: "memory");   // drain pending LDS DMA
#undef STAGE256

    #pragma unroll
    for (int m = 0; m < 8; ++m) {
        #pragma unroll
        for (int n = 0; n < 4; ++n) {
            #pragma unroll
            for (int r = 0; r < 4; ++r) {
                const int grow = row0 + wm*128 + m*16 + (lane >> 4) * 4 + r;
                const int gcol = col0 + wn*64 + n*16 + (lane & 15);
                const size_t idx = (size_t)grow * N + gcol;
                float v = acc[m][n][r];
                if (addf) v += addf[idx];
                if (addb) v += bf2f(addb[idx]);
                if (biasN) v += biasN[gcol];
                if (OUTF32) reinterpret_cast<float*>(Cv)[idx] = v;
                else        reinterpret_cast<u16*>(Cv)[idx] = f2bf(v);
            }
        }
    }
}

// ---------- launch ----------
extern "C" void kernel_launch(void* const* d_in, const int* in_sizes, int n_in,
                              void* d_out, int out_size, void* d_ws, size_t ws_size,
                              hipStream_t stream)
{
    const float* x          = (const float*)d_in[0];
    const float* gist_theta = (const float*)d_in[1];
    const float* gist_mag   = (const float*)d_in[2];
    const float* gist_wts   = (const float*)d_in[3];
    const float* ln_sheaf_w = (const float*)d_in[4];
    const float* ln_sheaf_b = (const float*)d_in[5];
    const float* sheaf_th   = (const float*)d_in[6];
    const float* alpha      = (const float*)d_in[7];
    const float* corr_W     = (const float*)d_in[8];
    const float* ln_gist_w  = (const float*)d_in[9];
    const float* ln_gist_b  = (const float*)d_in[10];
    const float* strength   = (const float*)d_in[11];
    const float* gr_w       = (const float*)d_in[12];
    const float* gr_b       = (const float*)d_in[13];
    const float* gca_w      = (const float*)d_in[14];
    const float* gca_b      = (const float*)d_in[15];
    const float* Wq         = (const float*)d_in[16];
    const float* Wk         = (const float*)d_in[17];
    const float* Wv         = (const float*)d_in[18];
    const float* Wo         = (const float*)d_in[19];
    const float* up_W       = (const float*)d_in[20];
    const float* up_b       = (const float*)d_in[21];
    float* out = (float*)d_out;

    static bool attr_done = false;
    if (!attr_done) {
        hipFuncSetAttribute((const void*)&gemm256_kernel<0>,
                            hipFuncAttributeMaxDynamicSharedMemorySize, 131072);
        hipFuncSetAttribute((const void*)&gemm256_kernel<1>,
                            hipFuncAttributeMaxDynamicSharedMemorySize, 131072);
        attr_done = true;
    }

    char* w = (char*)d_ws;
    const size_t BIG = (size_t)4 * 2048 * 2048 * sizeof(u16);  // 33.5 MB
    u16* wA = (u16*)(w);                 // x1 -> xA -> x2(in-place) -> ctx
    u16* wB = (u16*)(w + BIG);           // WkWv(16.8MB) -> pre -> Q
    u16* wC = (u16*)(w + 2*BIG);         // Abuf(pad) -> xB
    u16* wslot = (u16*)(w + 3*BIG);      // Bbuf(pad) / corr_W bf16 (8.4 MB)
    char* small = w + 3*BIG + (size_t)2048*2048*sizeof(u16);
    float* sheaf_cs = (float*)(small);
    float* gist_cs  = (float*)(small + 32768);
    u16* repr = (u16*)(small + 65536);            // 64x2048 bf16 (256 KB)
    u16* KV   = repr + 64*2048;                   // 64x4096 bf16 (512 KB)
    float* part = (float*)((char*)KV + (size_t)64*4096*sizeof(u16));  // K-split partials
    const size_t part_bytes = (size_t)8 * 64 * 4096 * sizeof(float);  // 8 MB max
    char* after_part = (char*)part + part_bytes;
    const bool ksplit = ws_size >= (size_t)(after_part - w);

    // dedicated slots for Wq / Wo bf16 (8.4 MB each) when workspace allows
    u16* wslot2 = (u16*)after_part;
    u16* wslot3 = wslot2 + (size_t)2048*2048;
    const bool roomy = ws_size >= (size_t)((char*)(wslot3 + (size_t)2048*2048) - w);

    const int W4 = 2048*2048/4;   // float4 groups per weight matrix
    const dim3 gBig256(2048/256, 8192/256), gKV(32, 1), gRepr(16, 1);

    setup_kernel<<<8, 256, 0, stream>>>(sheaf_th, gist_theta, gist_mag, gist_wts,
                                        strength, sheaf_cs, gist_cs);

    // hoisted batched weight converts (one dispatch for corr/Wq/Wo, one for Wk/Wv)
    if (roomy) {
        convert3_kernel<<<dim3(4096,3), 256, 0, stream>>>(corr_W, Wq, Wo,
                                                          wslot, wslot2, wslot3, W4);
    }
    convert2_kernel<<<dim3(4096,2), 256, 0, stream>>>(Wk, Wv,
                                                      wB, wB + (size_t)2048*2048, W4);

    // gist_repr = concat(theta,mag) @ up_W^T + up_b   (K padded to 1056)
    apad_kernel<<<64, 256, 0, stream>>>(gist_theta, gist_mag, wC);
    wpad_kernel<<<2048, 256, 0, stream>>>(up_W, roomy ? (u16*)((char*)wslot3 + (size_t)2048*2048*2) : wslot);
    // NOTE: when roomy, pad buffer must not clobber wslot (corr) — but the
    // extra slot may not exist; reuse wC? wC holds Abuf. Use repr? too small.
    // Safe choice: when roomy, place Bbuf(pad) after wslot3 only if it fits,
    // else fall back to wslot (and re-convert corr later).
    const bool padroom = ws_size >= (size_t)((char*)(wslot3 + (size_t)2048*2048) - w)
                         + (size_t)2048*1056*sizeof(u16);
    u16* padbuf = (roomy && padroom) ? (u16*)((char*)(wslot3 + (size_t)2048*2048)) : wslot;

    if (ksplit) {
        gemm_bt_kernel<2><<<dim3(16,1,4), 256, 0, stream>>>(wC, padbuf, part,
                                                 nullptr, nullptr, nullptr, 64, 2048, 1056);
        ksum_kernel<<<(64*2048/4 + 255)/256, 256, 0, stream>>>(part, 4, 64*2048/4, 2048,
                                                 up_b, repr);
    } else {
        gemm_bt_kernel<0><<<gRepr, 256, 0, stream>>>(wC, padbuf, repr, nullptr, nullptr, up_b,
                                                     64, 2048, 1056);
    }

    // KV = repr @ [Wk;Wv]^T  (one N=4096 GEMM; WkWv staged bf16 in wB)
    if (ksplit) {
        gemm_bt_kernel<2><<<dim3(32,1,8), 256, 0, stream>>>(repr, wB, part,
                                                 nullptr, nullptr, nullptr, 64, 4096, 2048);
        ksum_kernel<<<(64*4096/4 + 255)/256, 256, 0, stream>>>(part, 8, 64*4096/4, 4096,
                                                 nullptr, KV);
    } else {
        gemm_bt_kernel<0><<<gKV, 256, 0, stream>>>(repr, wB, KV, nullptr, nullptr, nullptr,
                                                   64, 4096, 2048);
    }

    ln_kernel<<<8192, 256, 0, stream>>>(x, ln_sheaf_w, ln_sheaf_b, wA);        // x1
    sheaf_kernel<<<8192, 256, 0, stream>>>(wA, sheaf_cs, alpha, wB);           // pre

    // corr GEMM: xA = x + pre + pre@corr^T
    if (!roomy || padbuf == wslot)   // wslot was consumed by pad buffer: (re)convert corr now
        convert_kernel<<<4096, 256, 0, stream>>>(corr_W, wslot, W4);
    gemm256_kernel<0><<<gBig256, 512, 131072, stream>>>(wB, wslot, wA, x, wB, nullptr,
                                                8192, 2048, 2048);
    stage2_kernel<<<8192, 256, 0, stream>>>(wA, gist_cs, ln_gist_w, ln_gist_b,
                                            gr_w, gr_b, gca_w, gca_b,
                                            wC, wA);                           // xB, x2
    // Q GEMM
    u16* qslot = roomy ? wslot2 : wslot;
    if (!roomy)
        convert_kernel<<<4096, 256, 0, stream>>>(Wq, wslot, W4);
    gemm256_kernel<0><<<gBig256, 512, 131072, stream>>>(wA, qslot, wB, nullptr, nullptr, nullptr,
                                                8192, 2048, 2048);
    attn_kernel<<<2048, 256, 0, stream>>>(wB, KV, wA);                         // ctx
    // Wo GEMM: out = xB + ctx@Wo^T
    u16* oslot = roomy ? wslot3 : wslot;
    if (!roomy)
        convert_kernel<<<4096, 256, 0, stream>>>(Wo, wslot, W4);
    gemm256_kernel<1><<<gBig256, 512, 131072, stream>>>(wA, oslot, (void*)out, nullptr, wC, nullptr,
                                                8192, 2048, 2048);
}